// Round 12
// baseline (198.854 us; speedup 1.0000x reference)
//
#include <hip/hip_runtime.h>
#include <math.h>

#ifdef __has_builtin
#if __has_builtin(__builtin_amdgcn_global_load_lds)
#define HAS_GLL 1
#endif
#endif
#ifndef HAS_GLL
#define HAS_GLL 0
#endif

typedef __attribute__((ext_vector_type(8))) short short8v;
typedef __attribute__((ext_vector_type(4))) float float4v;
typedef __attribute__((ext_vector_type(16))) float float16v;

__device__ __forceinline__ unsigned short f2bf(float f) {
    unsigned int u = __float_as_uint(f);
    u += 0x7fffu + ((u >> 16) & 1u);
    return (unsigned short)(u >> 16);
}

__device__ __forceinline__ float silu(float y) { return y / (1.f + expf(-y)); }

// wave stages 1KB into LDS: lane i -> ldsbase + 16*i, from per-lane gsrc (16B each)
__device__ __forceinline__ void stage1k(const void* gsrc, void* ldsbase) {
#if HAS_GLL
    __builtin_amdgcn_global_load_lds((const __attribute__((address_space(1))) unsigned int*)gsrc,
                                     (__attribute__((address_space(3))) unsigned int*)ldsbase,
                                     16, 0, 0);
#else
    int lane = threadIdx.x & 63;
    *(float4*)((char*)ldsbase + lane * 16) = *(const float4*)gsrc;
#endif
}

// ---------------- merged prep: A2 | A1 | A2off | xT ----------------
__global__ __launch_bounds__(256) void k_prep_all(const float* __restrict__ w_def,
                                                  const float* __restrict__ w_dc,
                                                  const float* __restrict__ w_off,
                                                  const float* __restrict__ x,
                                                  unsigned short* __restrict__ A1,
                                                  unsigned short* __restrict__ A2,
                                                  unsigned short* __restrict__ A2off,
                                                  unsigned short* __restrict__ xT) {
    int blk = blockIdx.x;
    int t = threadIdx.x;
    __shared__ unsigned short tl[32][36];
    if (blk < 4096) {
        int i = blk * 256 + t;
        int ci = i & 255;
        int tq = (i >> 8) & 3;
        int co = (i >> 10) & 255;
        int p  = i >> 18;
        int ph = p >> 1, pw = p & 1;
        int ty = tq >> 1, tx = tq & 1;
        int kh = 2 * ty + 1 - ph;
        int kw = 2 * tx + 1 - pw;
        A2[i] = f2bf(w_dc[((ci * 256 + co) * 4 + kh) * 4 + kw]);
    } else if (blk < 6400) {
        int i = (blk - 4096) * 256 + t;
        A1[i] = f2bf(w_def[i]);
    } else if (blk < 6688) {
        int i = (blk - 6400) * 256 + t;
        int slot = i & 31;
        int oc = (i >> 5) & 31;
        int rest = i >> 10;
        int tap = rest % 9;
        int cc8 = rest / 9;
        int cgrp = (slot >> 3) ^ ((oc >> 1) & 3);
        int c = cc8 * 32 + (cgrp << 3) + (slot & 7);
        unsigned short v = 0;
        if (oc < 18) v = f2bf(w_off[(size_t)oc * 2304 + c * 9 + tap]);
        A2off[i] = v;
    } else {
        int blk2 = blk - 6688;
        int hw0 = (blk2 & 31) * 32;
        int c0 = ((blk2 >> 5) & 7) * 32;
        int b = blk2 >> 8;
        {
            int c_l = t >> 3, w4 = (t & 7) * 4;
            float4 v = *(const float4*)&x[(size_t)((b * 256 + c0 + c_l) * 1024) + hw0 + w4];
            tl[c_l][w4 + 0] = f2bf(v.x);
            tl[c_l][w4 + 1] = f2bf(v.y);
            tl[c_l][w4 + 2] = f2bf(v.z);
            tl[c_l][w4 + 3] = f2bf(v.w);
        }
        __syncthreads();
        {
            int hw_l = t >> 3, c4 = (t & 7) * 4;
            unsigned int s0 = tl[c4 + 0][hw_l];
            unsigned int s1 = tl[c4 + 1][hw_l];
            unsigned int s2 = tl[c4 + 2][hw_l];
            unsigned int s3 = tl[c4 + 3][hw_l];
            uint2 pk;
            pk.x = s0 | (s1 << 16);
            pk.y = s2 | (s3 << 16);
            *(uint2*)&xT[(size_t)((b * 1024 + hw0 + hw_l) * 256) + c0 + c4] = pk;
        }
    }
}

// ---------------- offset conv as MFMA GEMM (unchanged, 16x16) ----------------
__global__ __launch_bounds__(256) void k_off_gemm(const unsigned short* __restrict__ A2off,
                                                  const unsigned short* __restrict__ xT,
                                                  const float* __restrict__ b_off,
                                                  float* __restrict__ off) {
    int hp = blockIdx.x, b = blockIdx.y;
    int h0 = hp * 2;
    int t = threadIdx.x;
    int lane = t & 63, wid = t >> 6;
    int l15 = lane & 15, g = lane >> 4;
    int swg = (l15 >> 1) & 3;
    __shared__ __align__(16) unsigned short As[9 * 32 * 32];
    __shared__ __align__(16) unsigned short Bsx[4 * 34 * 32];
    float4v acc[2];
    float4v z = {0.f, 0.f, 0.f, 0.f};
    acc[0] = z; acc[1] = z;

    int pos = wid * 16 + l15;
    int py = pos >> 5, px = pos & 31;

    for (int cc8 = 0; cc8 < 8; ++cc8) {
        __syncthreads();
        for (int idx = t; idx < 1152; idx += 256)
            stage1k(A2off + (size_t)cc8 * 9216 + idx * 8, (char*)As + idx * 16);
        for (int idx = t; idx < 544; idx += 256) {
            int r = idx / 136;
            int rem = idx - r * 136;
            int col = rem >> 2;
            int sgrp = rem & 3;
            int grp = sgrp ^ ((col >> 1) & 3);
            int h = h0 - 1 + r;
            int w = col - 1;
            uint4 v = {0u, 0u, 0u, 0u};
            if (h >= 0 && h < 32 && w >= 0 && w < 32)
                v = *(const uint4*)&xT[(size_t)((b * 1024 + h * 32 + w) * 256) + cc8 * 32 + grp * 8];
            *(uint4*)((char*)Bsx + ((r * 34 + col) << 6) + (sgrp << 4)) = v;
        }
        __syncthreads();
#pragma unroll
        for (int tap = 0; tap < 9; ++tap) {
            int ky = tap / 3, kx = tap - ky * 3;
            int col = px + kx;
            int rowr = py + ky;
            short8v bbf = *(const short8v*)((const char*)Bsx + ((rowr * 34 + col) << 6) +
                                            ((g ^ ((col >> 1) & 3)) << 4));
            short8v a0 = *(const short8v*)((const char*)As + tap * 2048 + l15 * 64 + ((g ^ swg) << 4));
            short8v a1 = *(const short8v*)((const char*)As + tap * 2048 + (16 + l15) * 64 + ((g ^ swg) << 4));
            acc[0] = __builtin_amdgcn_mfma_f32_16x16x32_bf16(a0, bbf, acc[0], 0, 0, 0);
            acc[1] = __builtin_amdgcn_mfma_f32_16x16x32_bf16(a1, bbf, acc[1], 0, 0, 0);
        }
    }
    int h = h0 + py;
#pragma unroll
    for (int r = 0; r < 4; ++r) {
        int oc = g * 4 + r;
        off[((size_t)(b * 18 + oc) << 10) + (h << 5) + px] = acc[0][r] + b_off[oc];
    }
    if (g == 0) {
#pragma unroll
        for (int r = 0; r < 2; ++r) {
            int oc = 16 + r;
            off[((size_t)(b * 18 + oc) << 10) + (h << 5) + px] = acc[1][r] + b_off[oc];
        }
    }
}

// ---------------- bilinear sampler (unchanged) ----------------
__global__ __launch_bounds__(576) void k_sample(const float* __restrict__ x,
                                                const float* __restrict__ off,
                                                unsigned short* __restrict__ S) {
    int cg = blockIdx.x, b = blockIdx.y, half = blockIdx.z;
    int cbase = cg * 8;
    int t = threadIdx.x;
    int k = t >> 6, lane = t & 63;
    __shared__ __align__(16) unsigned int xpl[4 * 1156];
    __shared__ __align__(16) unsigned short sS[72 * 66];

    for (int u = t; u < 1024; u += 576) {
        int p = u >> 8, row = (u >> 3) & 31, cq = (u & 7) << 2;
        const float* src0 = x + ((size_t)(b * 256 + cbase + 2 * p) << 10) + (row << 5) + cq;
        float4 a = *(const float4*)src0;
        float4 c = *(const float4*)(src0 + 1024);
        uint4 pk;
        pk.x = (unsigned int)f2bf(a.x) | ((unsigned int)f2bf(c.x) << 16);
        pk.y = (unsigned int)f2bf(a.y) | ((unsigned int)f2bf(c.y) << 16);
        pk.z = (unsigned int)f2bf(a.z) | ((unsigned int)f2bf(c.z) << 16);
        pk.w = (unsigned int)f2bf(a.w) | ((unsigned int)f2bf(c.w) << 16);
        *(uint4*)&xpl[p * 1156 + row * 36 + cq] = pk;
    }

    int wr_row = t / 9, wr_q = t - wr_row * 9;
    const float* offk0 = off + ((size_t)(b * 18 + 2 * k) << 10);
    const float* offk1 = off + ((size_t)(b * 18 + 2 * k + 1) << 10);
    int ky = k / 3 - 1, kx = k % 3 - 1;
    __syncthreads();

    for (int ci = 0; ci < 8; ++ci) {
        int chunk = half * 8 + ci;
        int pos = chunk * 64 + lane;
        int h = pos >> 5, w = pos & 31;
        float dy = offk0[pos];
        float dx = offk1[pos];
        float py = (float)(h + ky) + dy;
        float px = (float)(w + kx) + dx;
        float fy = floorf(py), fx = floorf(px);
        int y0i = (int)fy, x0i = (int)fx;
        float wy = py - fy, wxf = px - fx;
        float vy0 = (y0i >= 0 && y0i < 32) ? 1.f : 0.f;
        float vy1 = (y0i >= -1 && y0i < 31) ? 1.f : 0.f;
        float vx0 = (x0i >= 0 && x0i < 32) ? 1.f : 0.f;
        float vx1 = (x0i >= -1 && x0i < 31) ? 1.f : 0.f;
        int y0c = min(max(y0i, 0), 31), y1c = min(max(y0i + 1, 0), 31);
        int x0c = min(max(x0i, 0), 31), x1c = min(max(x0i + 1, 0), 31);
        float w00 = (1.f - wy) * (1.f - wxf) * vy0 * vx0;
        float w01 = (1.f - wy) * wxf * vy0 * vx1;
        float w10 = wy * (1.f - wxf) * vy1 * vx0;
        float w11 = wy * wxf * vy1 * vx1;
        int a00 = y0c * 36 + x0c, a01 = y0c * 36 + x1c;
        int a10 = y1c * 36 + x0c, a11 = y1c * 36 + x1c;
#pragma unroll
        for (int p = 0; p < 4; ++p) {
            const unsigned int* pl = xpl + p * 1156;
            unsigned int c00 = pl[a00], c01 = pl[a01], c10 = pl[a10], c11 = pl[a11];
            float e00 = __uint_as_float(c00 << 16), o00 = __uint_as_float(c00 & 0xFFFF0000u);
            float e01 = __uint_as_float(c01 << 16), o01 = __uint_as_float(c01 & 0xFFFF0000u);
            float e10 = __uint_as_float(c10 << 16), o10 = __uint_as_float(c10 & 0xFFFF0000u);
            float e11 = __uint_as_float(c11 << 16), o11 = __uint_as_float(c11 & 0xFFFF0000u);
            float ve = w00 * e00 + w01 * e01 + w10 * e10 + w11 * e11;
            float vo = w00 * o00 + w01 * o01 + w10 * o10 + w11 * o11;
            sS[((2 * p) * 9 + k) * 66 + lane] = f2bf(ve);
            sS[((2 * p + 1) * 9 + k) * 66 + lane] = f2bf(vo);
        }
        __syncthreads();
        {
            int basekc = wr_q * 8;
            unsigned int s0 = sS[(basekc + 0) * 66 + wr_row];
            unsigned int s1 = sS[(basekc + 1) * 66 + wr_row];
            unsigned int s2 = sS[(basekc + 2) * 66 + wr_row];
            unsigned int s3 = sS[(basekc + 3) * 66 + wr_row];
            unsigned int s4 = sS[(basekc + 4) * 66 + wr_row];
            unsigned int s5 = sS[(basekc + 5) * 66 + wr_row];
            unsigned int s6 = sS[(basekc + 6) * 66 + wr_row];
            unsigned int s7 = sS[(basekc + 7) * 66 + wr_row];
            uint4 qv;
            qv.x = s0 | (s1 << 16);
            qv.y = s2 | (s3 << 16);
            qv.z = s4 | (s5 << 16);
            qv.w = s6 | (s7 << 16);
            *(uint4*)(S + (size_t)(b * 1024 + chunk * 64 + wr_row) * 2304 + cg * 72 + wr_q * 8) = qv;
        }
        __syncthreads();
    }
}

// ---------------- GEMM1: BM=128, BN=64, KSTEP=64, dbuf, 32x32x16 MFMA; fused BN1; bf16 y1 ----------------
// grid (256 nb, 2 mb), 256 threads
__global__ __launch_bounds__(256) void k_gemm1(const unsigned short* __restrict__ A1,
                                               const unsigned short* __restrict__ S,
                                               const float* __restrict__ b_def,
                                               unsigned short* __restrict__ y1b,
                                               float* __restrict__ pstats1) {
    int nb = blockIdx.x, mb = blockIdx.y;
    int t = threadIdx.x;
    int lane = t & 63, wid = t >> 6;
    int wm = wid >> 1, wn = wid & 1;
    int l31 = lane & 31, hh = lane >> 5;
    __shared__ __align__(16) unsigned short As[2][8192];  // 128 x 64
    __shared__ __align__(16) unsigned short Bs[2][4096];  // 64 x 64
    int m0 = mb * 128, n0 = nb * 64;
    int b = n0 >> 10, pos0 = n0 & 1023;

    const unsigned short* srcA[4];
    int dA[4];
    const unsigned short* srcB[2];
    int dB[2];
#pragma unroll
    for (int it = 0; it < 4; ++it) {
        int idx = t + it * 256;
        int r = idx >> 3, s8 = idx & 7, c = s8 ^ (r & 7);
        srcA[it] = A1 + (size_t)(m0 + r) * 2304 + c * 8;
        dA[it] = idx * 8;
    }
#pragma unroll
    for (int it = 0; it < 2; ++it) {
        int idx = t + it * 256;
        int r = idx >> 3, s8 = idx & 7, c = s8 ^ (r & 7);
        srcB[it] = S + (size_t)(n0 + r) * 2304 + c * 8;
        dB[it] = idx * 8;
    }

    float16v acc[2];
#pragma unroll
    for (int i = 0; i < 2; ++i)
#pragma unroll
        for (int j = 0; j < 16; ++j) acc[i][j] = 0.f;

#pragma unroll
    for (int it = 0; it < 4; ++it) stage1k(srcA[it], &As[0][dA[it]]);
#pragma unroll
    for (int it = 0; it < 2; ++it) stage1k(srcB[it], &Bs[0][dB[it]]);
    __syncthreads();

    for (int step = 0; step < 36; ++step) {
        int cur = step & 1;
        if (step < 35) {
            int koff = (step + 1) * 64;
#pragma unroll
            for (int it = 0; it < 4; ++it) stage1k(srcA[it] + koff, &As[cur ^ 1][dA[it]]);
#pragma unroll
            for (int it = 0; it < 2; ++it) stage1k(srcB[it] + koff, &Bs[cur ^ 1][dB[it]]);
        }
        __builtin_amdgcn_s_setprio(1);
#pragma unroll
        for (int kk = 0; kk < 4; ++kk) {
            int browR = wn * 32 + l31;
            int bslot = ((kk << 1) + hh) ^ (browR & 7);
            short8v bb = *(const short8v*)((const char*)&Bs[cur][0] + browR * 128 + bslot * 16);
#pragma unroll
            for (int mi = 0; mi < 2; ++mi) {
                int row = wm * 64 + mi * 32 + l31;
                int slot = ((kk << 1) + hh) ^ (row & 7);
                short8v a = *(const short8v*)((const char*)&As[cur][0] + row * 128 + slot * 16);
                acc[mi] = __builtin_amdgcn_mfma_f32_32x32x16_bf16(a, bb, acc[mi], 0, 0, 0);
            }
        }
        __builtin_amdgcn_s_setprio(0);
        __syncthreads();
    }

    // epilogue: bias + bf16 write + BN1 partial stats (32x32 C/D layout)
    float* sred  = (float*)&As[0][0];  // [128][2]
    float* s2red = sred + 256;
#pragma unroll
    for (int mi = 0; mi < 2; ++mi) {
#pragma unroll
        for (int reg = 0; reg < 16; ++reg) {
            int rowf = (reg & 3) + 8 * (reg >> 2) + 4 * hh;
            int co = m0 + wm * 64 + mi * 32 + rowf;
            float v = acc[mi][reg] + b_def[co];
            y1b[((size_t)(b * 256 + co) << 10) + pos0 + wn * 32 + l31] = f2bf(v);
            float s = v, s2 = v * v;
#pragma unroll
            for (int m = 16; m >= 1; m >>= 1) {
                s  += __shfl_xor(s, m, 64);
                s2 += __shfl_xor(s2, m, 64);
            }
            if (l31 == 0) {
                int col = co - m0;
                sred[col * 2 + wn]  = s;
                s2red[col * 2 + wn] = s2;
            }
        }
    }
    __syncthreads();
    if (t < 128) {
        float s  = sred[t * 2] + sred[t * 2 + 1];
        float s2 = s2red[t * 2] + s2red[t * 2 + 1];
        int ch = m0 + t;
        pstats1[ch * 256 + nb] = s;
        pstats1[65536 + ch * 256 + nb] = s2;
    }
}

// ---------------- GEMM2: convT by parity, KSTEP=64, dbuf, 32x32x16 MFMA, bf16 outP, fused BN2 ----------------
__global__ __launch_bounds__(256) void k_gemm2(const unsigned short* __restrict__ A2,
                                               const unsigned short* __restrict__ y1T,
                                               unsigned short* __restrict__ outP,
                                               float* __restrict__ pstats2) {
    int nb = blockIdx.x, mb = blockIdx.y, p = blockIdx.z;
    int ph = p >> 1, pw = p & 1;
    int t = threadIdx.x;
    int lane = t & 63, wid = t >> 6;
    int wm = wid >> 1, wn = wid & 1;
    int l31 = lane & 31, hh = lane >> 5;
    __shared__ __align__(16) unsigned short As[2][8192];
    __shared__ __align__(16) unsigned short Bs[2][8192];
    int m0 = mb * 128, n0 = nb * 128;
    int b = n0 >> 10, pos0 = n0 & 1023, oh0 = pos0 >> 5;

    int dtab[4];
#pragma unroll
    for (int tap = 0; tap < 4; ++tap) {
        int ty = tap >> 1, tx = tap & 1;
        int dy = ph ? (1 - ty) : (-ty);
        int dx = pw ? (1 - tx) : (-tx);
        dtab[tap] = (dy * 34 + dx) * 256;
    }
    const unsigned short* srcA[4];
    const unsigned short* srcB[4];
    int dstoff[4];
#pragma unroll
    for (int it = 0; it < 4; ++it) {
        int idx = t + it * 256;
        int r = idx >> 3, s8 = idx & 7, c = s8 ^ (r & 7);
        srcA[it] = A2 + (size_t)(p * 256 + m0 + r) * 1024 + c * 8;
        int ih = oh0 + (r >> 5) + 1;
        int iw = (r & 31) + 1;
        srcB[it] = y1T + ((size_t)(b * 34 + ih) * 34 + iw) * 256 + c * 8;
        dstoff[it] = idx * 8;
    }

    float16v acc[2][2];
#pragma unroll
    for (int i = 0; i < 2; ++i)
#pragma unroll
        for (int j = 0; j < 2; ++j)
#pragma unroll
            for (int q = 0; q < 16; ++q) acc[i][j][q] = 0.f;

#pragma unroll
    for (int it = 0; it < 4; ++it) {
        stage1k(srcA[it], &As[0][dstoff[it]]);
        stage1k(srcB[it] + dtab[0], &Bs[0][dstoff[it]]);
    }
    __syncthreads();

#pragma unroll
    for (int step = 0; step < 16; ++step) {
        int cur = step & 1;
        if (step < 15) {
            int ns = step + 1;
            int tap = ns >> 2;
            int koff = ns * 64;
            int boff = dtab[tap] + (ns & 3) * 64;
#pragma unroll
            for (int it = 0; it < 4; ++it) {
                stage1k(srcA[it] + koff, &As[cur ^ 1][dstoff[it]]);
                stage1k(srcB[it] + boff, &Bs[cur ^ 1][dstoff[it]]);
            }
        }
        __builtin_amdgcn_s_setprio(1);
#pragma unroll
        for (int kk = 0; kk < 4; ++kk) {
            short8v a[2], bb[2];
#pragma unroll
            for (int mi = 0; mi < 2; ++mi) {
                int row = wm * 64 + mi * 32 + l31;
                int slot = ((kk << 1) + hh) ^ (row & 7);
                a[mi] = *(const short8v*)((const char*)&As[cur][0] + row * 128 + slot * 16);
            }
#pragma unroll
            for (int ni = 0; ni < 2; ++ni) {
                int row = wn * 64 + ni * 32 + l31;
                int slot = ((kk << 1) + hh) ^ (row & 7);
                bb[ni] = *(const short8v*)((const char*)&Bs[cur][0] + row * 128 + slot * 16);
            }
#pragma unroll
            for (int mi = 0; mi < 2; ++mi)
#pragma unroll
                for (int ni = 0; ni < 2; ++ni)
                    acc[mi][ni] = __builtin_amdgcn_mfma_f32_32x32x16_bf16(a[mi], bb[ni], acc[mi][ni], 0, 0, 0);
        }
        __builtin_amdgcn_s_setprio(0);
        __syncthreads();
    }
    // bf16 write to parity-planar outP (32x32 C/D layout)
#pragma unroll
    for (int mi = 0; mi < 2; ++mi) {
#pragma unroll
        for (int reg = 0; reg < 16; ++reg) {
            int rowf = (reg & 3) + 8 * (reg >> 2) + 4 * hh;
            int co = m0 + wm * 64 + mi * 32 + rowf;
            unsigned short* dst = outP + ((size_t)((p * 16 + b) * 256 + co) << 10) + pos0;
#pragma unroll
            for (int ni = 0; ni < 2; ++ni)
                dst[wn * 64 + ni * 32 + l31] = f2bf(acc[mi][ni][reg]);
        }
    }
    // fused BN2 partial stats (from fp32 accs)
    float* sred  = (float*)&As[0][0];
    float* s2red = sred + 256;
#pragma unroll
    for (int mi = 0; mi < 2; ++mi) {
#pragma unroll
        for (int reg = 0; reg < 16; ++reg) {
            int rowf = (reg & 3) + 8 * (reg >> 2) + 4 * hh;
            float v0 = acc[mi][0][reg];
            float v1 = acc[mi][1][reg];
            float s = v0 + v1;
            float s2 = v0 * v0 + v1 * v1;
#pragma unroll
            for (int m = 16; m >= 1; m >>= 1) {
                s  += __shfl_xor(s, m, 64);
                s2 += __shfl_xor(s2, m, 64);
            }
            if (l31 == 0) {
                int col = wm * 64 + mi * 32 + rowf;
                sred[col * 2 + wn]  = s;
                s2red[col * 2 + wn] = s2;
            }
        }
    }
    __syncthreads();
    if (t < 128) {
        float s  = sred[t * 2] + sred[t * 2 + 1];
        float s2 = s2red[t * 2] + s2red[t * 2 + 1];
        int row = p * 128 + nb;
        int ch = m0 + t;
        pstats2[ch * 512 + row] = s;
        pstats2[131072 + ch * 512 + row] = s2;
    }
}

// ---------------- parallel BN finisher ----------------
__global__ __launch_bounds__(256) void k_bnfin_par(const float* __restrict__ pstats, int nparts,
                                                   float n,
                                                   float* __restrict__ mean, float* __restrict__ rstd) {
    int ch = blockIdx.x;
    int t = threadIdx.x;
    float s = 0.f, s2 = 0.f;
    for (int j = t; j < nparts; j += 256) {
        s  += pstats[ch * nparts + j];
        s2 += pstats[256 * nparts + ch * nparts + j];
    }
    __shared__ float rs[256], rs2[256];
    rs[t] = s; rs2[t] = s2;
    __syncthreads();
    for (int d = 128; d > 0; d >>= 1) {
        if (t < d) { rs[t] += rs[t + d]; rs2[t] += rs2[t + d]; }
        __syncthreads();
    }
    if (t == 0) {
        float m = rs[0] / n;
        float var = rs2[0] / n - m * m;
        mean[ch] = m;
        rstd[ch] = rsqrtf(var + 1e-5f);
    }
}

// ---------------- BN+SiLU on bf16 y1 -> channel-last padded bf16 y1T, halo zeroed ----------------
__global__ __launch_bounds__(256) void k_bnsilu_padT(const unsigned short* __restrict__ y1b,
                                                     const float* __restrict__ mean,
                                                     const float* __restrict__ rstd,
                                                     const float* __restrict__ gamma,
                                                     const float* __restrict__ beta,
                                                     unsigned short* __restrict__ y1T) {
    int py = blockIdx.x, cg = blockIdx.y, b = blockIdx.z;
    int c0 = cg * 32;
    int t = threadIdx.x;
    uint2 zz; zz.x = 0u; zz.y = 0u;
    if (py == 0 || py == 33) {
        for (int u = t; u < 272; u += 256) {
            int col = u >> 3, c4 = (u & 7) * 4;
            *(uint2*)&y1T[((size_t)(b * 34 + py) * 34 + col) * 256 + c0 + c4] = zz;
        }
        return;
    }
    __shared__ unsigned short tl[32][36];
    int iy = py - 1;
    {
        int c_l = t >> 3, px4 = (t & 7) * 4;
        int ch = c0 + c_l;
        float m = mean[ch], rs = rstd[ch], ga = gamma[ch], be = beta[ch];
        uint2 v = *(const uint2*)&y1b[(size_t)((b * 256 + ch) << 10) + (iy << 5) + px4];
        float f0 = __uint_as_float(v.x << 16), f1 = __uint_as_float(v.x & 0xFFFF0000u);
        float f2 = __uint_as_float(v.y << 16), f3 = __uint_as_float(v.y & 0xFFFF0000u);
        tl[c_l][px4 + 0] = f2bf(silu(ga * (f0 - m) * rs + be));
        tl[c_l][px4 + 1] = f2bf(silu(ga * (f1 - m) * rs + be));
        tl[c_l][px4 + 2] = f2bf(silu(ga * (f2 - m) * rs + be));
        tl[c_l][px4 + 3] = f2bf(silu(ga * (f3 - m) * rs + be));
    }
    __syncthreads();
    {
        int px = t >> 3, c4 = (t & 7) * 4;
        unsigned int s0 = tl[c4 + 0][px];
        unsigned int s1 = tl[c4 + 1][px];
        unsigned int s2 = tl[c4 + 2][px];
        unsigned int s3 = tl[c4 + 3][px];
        uint2 pk;
        pk.x = s0 | (s1 << 16);
        pk.y = s2 | (s3 << 16);
        *(uint2*)&y1T[((size_t)(b * 34 + py) * 34 + (px + 1)) * 256 + c0 + c4] = pk;
    }
    if (t < 16) {
        int col = (t >> 3) ? 33 : 0;
        int c4 = (t & 7) * 4;
        *(uint2*)&y1T[((size_t)(b * 34 + py) * 34 + col) * 256 + c0 + c4] = zz;
    }
}

// ---------------- final: BN+SiLU + parity interleave (bf16 outP) -> out ----------------
__global__ __launch_bounds__(256) void k_bnsilu_out(const unsigned short* __restrict__ outP,
                                                    const float* __restrict__ mean,
                                                    const float* __restrict__ rstd,
                                                    const float* __restrict__ gamma,
                                                    const float* __restrict__ beta,
                                                    float* __restrict__ out) {
    unsigned int i = blockIdx.x * 256 + threadIdx.x;
    int ow4 = i & 15;
    int oh = (i >> 4) & 63;
    int co = (i >> 10) & 255;
    int b  = i >> 18;
    int p0 = (oh & 1) * 2;
    int pos = ((oh >> 1) << 5) + ow4 * 2;
    const unsigned short* pl0 = outP + ((size_t)((p0 * 16 + b) * 256 + co) << 10) + pos;
    const unsigned short* pl1 = pl0 + ((size_t)16 * 256 << 10);
    unsigned int ue = *(const unsigned int*)pl0;
    unsigned int uo = *(const unsigned int*)pl1;
    float ex = __uint_as_float(ue << 16), ey = __uint_as_float(ue & 0xFFFF0000u);
    float ox = __uint_as_float(uo << 16), oy = __uint_as_float(uo & 0xFFFF0000u);
    float m = mean[co], rs = rstd[co], ga = gamma[co], be = beta[co];
    float4 v;
    v.x = silu(ga * (ex - m) * rs + be);
    v.y = silu(ga * (ox - m) * rs + be);
    v.z = silu(ga * (ey - m) * rs + be);
    v.w = silu(ga * (oy - m) * rs + be);
    *(float4*)&out[((size_t)(b * 256 + co) << 12) + (oh << 6) + ow4 * 4] = v;
}

extern "C" void kernel_launch(void* const* d_in, const int* in_sizes, int n_in,
                              void* d_out, int out_size, void* d_ws, size_t ws_size,
                              hipStream_t stream) {
    const float* x      = (const float*)d_in[0];
    const float* w_off  = (const float*)d_in[1];
    const float* b_off  = (const float*)d_in[2];
    const float* w_def  = (const float*)d_in[3];
    const float* b_def  = (const float*)d_in[4];
    const float* gamma1 = (const float*)d_in[5];
    const float* beta1  = (const float*)d_in[6];
    const float* w_dc   = (const float*)d_in[7];
    const float* gamma2 = (const float*)d_in[8];
    const float* beta2  = (const float*)d_in[9];
    float* out = (float*)d_out;

    char* base = (char*)d_ws;
    unsigned short* S    = (unsigned short*)base;                 // 75,497,472 B (dead after gemm1)
    unsigned short* y1b  = (unsigned short*)(base + 75497472);    //  8,388,608 B (bf16 now)
    unsigned short* y1T  = (unsigned short*)(base + 92274688);    //  9,469,952 B (padded ch-last)
    unsigned short* A1   = (unsigned short*)(base + 101744640);   //  1,179,648 B
    unsigned short* A2   = (unsigned short*)(base + 102924288);   //  2,097,152 B
    float*          off  = (float*)(base + 105021440);            //  1,179,648 B
    float*          stats = (float*)(base + 106201088);           //  1,024 B
    float* mean1 = stats, *rstd1 = stats + 256, *mean2 = stats + 512, *rstd2 = stats + 768;
    float* pstats1 = off;
    float* pstats2 = off;
    unsigned short* xT    = (unsigned short*)base;                //  8,388,608 B (dead after off_gemm)
    unsigned short* A2off = (unsigned short*)(base + 8388608);    //    147,456 B
    unsigned short* outP = (unsigned short*)base;  // 33,554,432 B, aliases S after gemm1

    k_prep_all<<<10784, 256, 0, stream>>>(w_def, w_dc, w_off, x, A1, A2, A2off, xT);
    k_off_gemm<<<dim3(16, 16), 256, 0, stream>>>(A2off, xT, b_off, off);
    k_sample<<<dim3(32, 16, 2), 576, 0, stream>>>(x, off, S);
    k_gemm1<<<dim3(256, 2), 256, 0, stream>>>(A1, S, b_def, y1b, pstats1);
    k_bnfin_par<<<256, 256, 0, stream>>>(pstats1, 256, 16384.f, mean1, rstd1);
    k_bnsilu_padT<<<dim3(34, 8, 16), 256, 0, stream>>>(y1b, mean1, rstd1, gamma1, beta1, y1T);
    k_gemm2<<<dim3(128, 2, 4), 256, 0, stream>>>(A2, y1T, outP, pstats2);
    k_bnfin_par<<<256, 256, 0, stream>>>(pstats2, 512, 65536.f, mean2, rstd2);
    k_bnsilu_out<<<16384, 256, 0, stream>>>(outP, mean2, rstd2, gamma2, beta2, out);
}

// Round 13
// 184.674 us; speedup vs baseline: 1.0768x; 1.0768x over previous
//
#include <hip/hip_runtime.h>
#include <math.h>

#ifdef __has_builtin
#if __has_builtin(__builtin_amdgcn_global_load_lds)
#define HAS_GLL 1
#endif
#endif
#ifndef HAS_GLL
#define HAS_GLL 0
#endif

typedef __attribute__((ext_vector_type(8))) short short8v;
typedef __attribute__((ext_vector_type(4))) float float4v;

__device__ __forceinline__ unsigned short f2bf(float f) {
    unsigned int u = __float_as_uint(f);
    u += 0x7fffu + ((u >> 16) & 1u);
    return (unsigned short)(u >> 16);
}

__device__ __forceinline__ float silu(float y) { return y / (1.f + expf(-y)); }

// wave stages 1KB into LDS: lane i -> ldsbase + 16*i, from per-lane gsrc (16B each)
__device__ __forceinline__ void stage1k(const void* gsrc, void* ldsbase) {
#if HAS_GLL
    __builtin_amdgcn_global_load_lds((const __attribute__((address_space(1))) unsigned int*)gsrc,
                                     (__attribute__((address_space(3))) unsigned int*)ldsbase,
                                     16, 0, 0);
#else
    int lane = threadIdx.x & 63;
    *(float4*)((char*)ldsbase + lane * 16) = *(const float4*)gsrc;
#endif
}

// ---------------- merged prep: A2 | A1 | A2off | xT ----------------
__global__ __launch_bounds__(256) void k_prep_all(const float* __restrict__ w_def,
                                                  const float* __restrict__ w_dc,
                                                  const float* __restrict__ w_off,
                                                  const float* __restrict__ x,
                                                  unsigned short* __restrict__ A1,
                                                  unsigned short* __restrict__ A2,
                                                  unsigned short* __restrict__ A2off,
                                                  unsigned short* __restrict__ xT) {
    int blk = blockIdx.x;
    int t = threadIdx.x;
    __shared__ unsigned short tl[32][36];
    if (blk < 4096) {
        int i = blk * 256 + t;
        int ci = i & 255;
        int tq = (i >> 8) & 3;
        int co = (i >> 10) & 255;
        int p  = i >> 18;
        int ph = p >> 1, pw = p & 1;
        int ty = tq >> 1, tx = tq & 1;
        int kh = 2 * ty + 1 - ph;
        int kw = 2 * tx + 1 - pw;
        A2[i] = f2bf(w_dc[((ci * 256 + co) * 4 + kh) * 4 + kw]);
    } else if (blk < 6400) {
        int i = (blk - 4096) * 256 + t;
        A1[i] = f2bf(w_def[i]);
    } else if (blk < 6688) {
        int i = (blk - 6400) * 256 + t;
        int slot = i & 31;
        int oc = (i >> 5) & 31;
        int rest = i >> 10;
        int tap = rest % 9;
        int cc8 = rest / 9;
        int cgrp = (slot >> 3) ^ ((oc >> 1) & 3);
        int c = cc8 * 32 + (cgrp << 3) + (slot & 7);
        unsigned short v = 0;
        if (oc < 18) v = f2bf(w_off[(size_t)oc * 2304 + c * 9 + tap]);
        A2off[i] = v;
    } else {
        int blk2 = blk - 6688;
        int hw0 = (blk2 & 31) * 32;
        int c0 = ((blk2 >> 5) & 7) * 32;
        int b = blk2 >> 8;
        {
            int c_l = t >> 3, w4 = (t & 7) * 4;
            float4 v = *(const float4*)&x[(size_t)((b * 256 + c0 + c_l) * 1024) + hw0 + w4];
            tl[c_l][w4 + 0] = f2bf(v.x);
            tl[c_l][w4 + 1] = f2bf(v.y);
            tl[c_l][w4 + 2] = f2bf(v.z);
            tl[c_l][w4 + 3] = f2bf(v.w);
        }
        __syncthreads();
        {
            int hw_l = t >> 3, c4 = (t & 7) * 4;
            unsigned int s0 = tl[c4 + 0][hw_l];
            unsigned int s1 = tl[c4 + 1][hw_l];
            unsigned int s2 = tl[c4 + 2][hw_l];
            unsigned int s3 = tl[c4 + 3][hw_l];
            uint2 pk;
            pk.x = s0 | (s1 << 16);
            pk.y = s2 | (s3 << 16);
            *(uint2*)&xT[(size_t)((b * 1024 + hw0 + hw_l) * 256) + c0 + c4] = pk;
        }
    }
}

// ---------------- offset conv as MFMA GEMM ----------------
__global__ __launch_bounds__(256) void k_off_gemm(const unsigned short* __restrict__ A2off,
                                                  const unsigned short* __restrict__ xT,
                                                  const float* __restrict__ b_off,
                                                  float* __restrict__ off) {
    int hp = blockIdx.x, b = blockIdx.y;
    int h0 = hp * 2;
    int t = threadIdx.x;
    int lane = t & 63, wid = t >> 6;
    int l15 = lane & 15, g = lane >> 4;
    int swg = (l15 >> 1) & 3;
    __shared__ __align__(16) unsigned short As[9 * 32 * 32];
    __shared__ __align__(16) unsigned short Bsx[4 * 34 * 32];
    float4v acc[2];
    float4v z = {0.f, 0.f, 0.f, 0.f};
    acc[0] = z; acc[1] = z;

    int pos = wid * 16 + l15;
    int py = pos >> 5, px = pos & 31;

    for (int cc8 = 0; cc8 < 8; ++cc8) {
        __syncthreads();
        for (int idx = t; idx < 1152; idx += 256)
            stage1k(A2off + (size_t)cc8 * 9216 + idx * 8, (char*)As + idx * 16);
        for (int idx = t; idx < 544; idx += 256) {
            int r = idx / 136;
            int rem = idx - r * 136;
            int col = rem >> 2;
            int sgrp = rem & 3;
            int grp = sgrp ^ ((col >> 1) & 3);
            int h = h0 - 1 + r;
            int w = col - 1;
            uint4 v = {0u, 0u, 0u, 0u};
            if (h >= 0 && h < 32 && w >= 0 && w < 32)
                v = *(const uint4*)&xT[(size_t)((b * 1024 + h * 32 + w) * 256) + cc8 * 32 + grp * 8];
            *(uint4*)((char*)Bsx + ((r * 34 + col) << 6) + (sgrp << 4)) = v;
        }
        __syncthreads();
#pragma unroll
        for (int tap = 0; tap < 9; ++tap) {
            int ky = tap / 3, kx = tap - ky * 3;
            int col = px + kx;
            int rowr = py + ky;
            short8v bbf = *(const short8v*)((const char*)Bsx + ((rowr * 34 + col) << 6) +
                                            ((g ^ ((col >> 1) & 3)) << 4));
            short8v a0 = *(const short8v*)((const char*)As + tap * 2048 + l15 * 64 + ((g ^ swg) << 4));
            short8v a1 = *(const short8v*)((const char*)As + tap * 2048 + (16 + l15) * 64 + ((g ^ swg) << 4));
            acc[0] = __builtin_amdgcn_mfma_f32_16x16x32_bf16(a0, bbf, acc[0], 0, 0, 0);
            acc[1] = __builtin_amdgcn_mfma_f32_16x16x32_bf16(a1, bbf, acc[1], 0, 0, 0);
        }
    }
    int h = h0 + py;
#pragma unroll
    for (int r = 0; r < 4; ++r) {
        int oc = g * 4 + r;
        off[((size_t)(b * 18 + oc) << 10) + (h << 5) + px] = acc[0][r] + b_off[oc];
    }
    if (g == 0) {
#pragma unroll
        for (int r = 0; r < 2; ++r) {
            int oc = 16 + r;
            off[((size_t)(b * 18 + oc) << 10) + (h << 5) + px] = acc[1][r] + b_off[oc];
        }
    }
}

// ---------------- bilinear sampler ----------------
__global__ __launch_bounds__(576) void k_sample(const float* __restrict__ x,
                                                const float* __restrict__ off,
                                                unsigned short* __restrict__ S) {
    int cg = blockIdx.x, b = blockIdx.y, half = blockIdx.z;
    int cbase = cg * 8;
    int t = threadIdx.x;
    int k = t >> 6, lane = t & 63;
    __shared__ __align__(16) unsigned int xpl[4 * 1156];
    __shared__ __align__(16) unsigned short sS[72 * 66];

    for (int u = t; u < 1024; u += 576) {
        int p = u >> 8, row = (u >> 3) & 31, cq = (u & 7) << 2;
        const float* src0 = x + ((size_t)(b * 256 + cbase + 2 * p) << 10) + (row << 5) + cq;
        float4 a = *(const float4*)src0;
        float4 c = *(const float4*)(src0 + 1024);
        uint4 pk;
        pk.x = (unsigned int)f2bf(a.x) | ((unsigned int)f2bf(c.x) << 16);
        pk.y = (unsigned int)f2bf(a.y) | ((unsigned int)f2bf(c.y) << 16);
        pk.z = (unsigned int)f2bf(a.z) | ((unsigned int)f2bf(c.z) << 16);
        pk.w = (unsigned int)f2bf(a.w) | ((unsigned int)f2bf(c.w) << 16);
        *(uint4*)&xpl[p * 1156 + row * 36 + cq] = pk;
    }

    int wr_row = t / 9, wr_q = t - wr_row * 9;
    const float* offk0 = off + ((size_t)(b * 18 + 2 * k) << 10);
    const float* offk1 = off + ((size_t)(b * 18 + 2 * k + 1) << 10);
    int ky = k / 3 - 1, kx = k % 3 - 1;
    __syncthreads();

    for (int ci = 0; ci < 8; ++ci) {
        int chunk = half * 8 + ci;
        int pos = chunk * 64 + lane;
        int h = pos >> 5, w = pos & 31;
        float dy = offk0[pos];
        float dx = offk1[pos];
        float py = (float)(h + ky) + dy;
        float px = (float)(w + kx) + dx;
        float fy = floorf(py), fx = floorf(px);
        int y0i = (int)fy, x0i = (int)fx;
        float wy = py - fy, wxf = px - fx;
        float vy0 = (y0i >= 0 && y0i < 32) ? 1.f : 0.f;
        float vy1 = (y0i >= -1 && y0i < 31) ? 1.f : 0.f;
        float vx0 = (x0i >= 0 && x0i < 32) ? 1.f : 0.f;
        float vx1 = (x0i >= -1 && x0i < 31) ? 1.f : 0.f;
        int y0c = min(max(y0i, 0), 31), y1c = min(max(y0i + 1, 0), 31);
        int x0c = min(max(x0i, 0), 31), x1c = min(max(x0i + 1, 0), 31);
        float w00 = (1.f - wy) * (1.f - wxf) * vy0 * vx0;
        float w01 = (1.f - wy) * wxf * vy0 * vx1;
        float w10 = wy * (1.f - wxf) * vy1 * vx0;
        float w11 = wy * wxf * vy1 * vx1;
        int a00 = y0c * 36 + x0c, a01 = y0c * 36 + x1c;
        int a10 = y1c * 36 + x0c, a11 = y1c * 36 + x1c;
#pragma unroll
        for (int p = 0; p < 4; ++p) {
            const unsigned int* pl = xpl + p * 1156;
            unsigned int c00 = pl[a00], c01 = pl[a01], c10 = pl[a10], c11 = pl[a11];
            float e00 = __uint_as_float(c00 << 16), o00 = __uint_as_float(c00 & 0xFFFF0000u);
            float e01 = __uint_as_float(c01 << 16), o01 = __uint_as_float(c01 & 0xFFFF0000u);
            float e10 = __uint_as_float(c10 << 16), o10 = __uint_as_float(c10 & 0xFFFF0000u);
            float e11 = __uint_as_float(c11 << 16), o11 = __uint_as_float(c11 & 0xFFFF0000u);
            float ve = w00 * e00 + w01 * e01 + w10 * e10 + w11 * e11;
            float vo = w00 * o00 + w01 * o01 + w10 * o10 + w11 * o11;
            sS[((2 * p) * 9 + k) * 66 + lane] = f2bf(ve);
            sS[((2 * p + 1) * 9 + k) * 66 + lane] = f2bf(vo);
        }
        __syncthreads();
        {
            int basekc = wr_q * 8;
            unsigned int s0 = sS[(basekc + 0) * 66 + wr_row];
            unsigned int s1 = sS[(basekc + 1) * 66 + wr_row];
            unsigned int s2 = sS[(basekc + 2) * 66 + wr_row];
            unsigned int s3 = sS[(basekc + 3) * 66 + wr_row];
            unsigned int s4 = sS[(basekc + 4) * 66 + wr_row];
            unsigned int s5 = sS[(basekc + 5) * 66 + wr_row];
            unsigned int s6 = sS[(basekc + 6) * 66 + wr_row];
            unsigned int s7 = sS[(basekc + 7) * 66 + wr_row];
            uint4 qv;
            qv.x = s0 | (s1 << 16);
            qv.y = s2 | (s3 << 16);
            qv.z = s4 | (s5 << 16);
            qv.w = s6 | (s7 << 16);
            *(uint4*)(S + (size_t)(b * 1024 + chunk * 64 + wr_row) * 2304 + cg * 72 + wr_q * 8) = qv;
        }
        __syncthreads();
    }
}

// ---------------- GEMM1: BM=128, BN=64, KSTEP=64, dbuf, 16x16 MFMA; fused BN1; bf16 y1 ----------------
// grid (256 nb, 2 mb), 256 threads
__global__ __launch_bounds__(256) void k_gemm1(const unsigned short* __restrict__ A1,
                                               const unsigned short* __restrict__ S,
                                               const float* __restrict__ b_def,
                                               unsigned short* __restrict__ y1b,
                                               float* __restrict__ pstats1) {
    int nb = blockIdx.x, mb = blockIdx.y;
    int t = threadIdx.x;
    int lane = t & 63, wid = t >> 6;
    int wm = wid >> 1, wn = wid & 1;
    int l15 = lane & 15, g = lane >> 4;
    __shared__ __align__(16) unsigned short As[2][8192];  // 128 x 64
    __shared__ __align__(16) unsigned short Bs[2][4096];  // 64 x 64
    int m0 = mb * 128, n0 = nb * 64;
    int b = n0 >> 10, pos0 = n0 & 1023;

    const unsigned short* srcA[4];
    int dA[4];
    const unsigned short* srcB[2];
    int dB[2];
#pragma unroll
    for (int it = 0; it < 4; ++it) {
        int idx = t + it * 256;
        int r = idx >> 3, s8 = idx & 7, c = s8 ^ (r & 7);
        srcA[it] = A1 + (size_t)(m0 + r) * 2304 + c * 8;
        dA[it] = idx * 8;
    }
#pragma unroll
    for (int it = 0; it < 2; ++it) {
        int idx = t + it * 256;
        int r = idx >> 3, s8 = idx & 7, c = s8 ^ (r & 7);
        srcB[it] = S + (size_t)(n0 + r) * 2304 + c * 8;
        dB[it] = idx * 8;
    }

    float4v acc[4][2];
    float4v z = {0.f, 0.f, 0.f, 0.f};
#pragma unroll
    for (int i = 0; i < 4; ++i) { acc[i][0] = z; acc[i][1] = z; }

#pragma unroll
    for (int it = 0; it < 4; ++it) stage1k(srcA[it], &As[0][dA[it]]);
#pragma unroll
    for (int it = 0; it < 2; ++it) stage1k(srcB[it], &Bs[0][dB[it]]);
    __syncthreads();

    for (int step = 0; step < 36; ++step) {
        int cur = step & 1;
        if (step < 35) {
            int koff = (step + 1) * 64;
#pragma unroll
            for (int it = 0; it < 4; ++it) stage1k(srcA[it] + koff, &As[cur ^ 1][dA[it]]);
#pragma unroll
            for (int it = 0; it < 2; ++it) stage1k(srcB[it] + koff, &Bs[cur ^ 1][dB[it]]);
        }
        __builtin_amdgcn_s_setprio(1);
#pragma unroll
        for (int kk = 0; kk < 2; ++kk) {
            short8v a[4], bb[2];
#pragma unroll
            for (int mi = 0; mi < 4; ++mi) {
                int row = wm * 64 + mi * 16 + l15;
                int slot = ((kk << 2) + g) ^ (row & 7);
                a[mi] = *(const short8v*)((const char*)&As[cur][0] + row * 128 + slot * 16);
            }
#pragma unroll
            for (int ni = 0; ni < 2; ++ni) {
                int row = wn * 32 + ni * 16 + l15;
                int slot = ((kk << 2) + g) ^ (row & 7);
                bb[ni] = *(const short8v*)((const char*)&Bs[cur][0] + row * 128 + slot * 16);
            }
#pragma unroll
            for (int mi = 0; mi < 4; ++mi)
#pragma unroll
                for (int ni = 0; ni < 2; ++ni)
                    acc[mi][ni] = __builtin_amdgcn_mfma_f32_16x16x32_bf16(a[mi], bb[ni], acc[mi][ni], 0, 0, 0);
        }
        __builtin_amdgcn_s_setprio(0);
        __syncthreads();
    }

    // epilogue: bias + bf16 write + BN1 partial stats
    float* sred  = (float*)&As[0][0];  // [128][2]
    float* s2red = sred + 256;
#pragma unroll
    for (int mi = 0; mi < 4; ++mi) {
#pragma unroll
        for (int r = 0; r < 4; ++r) {
            int co = m0 + wm * 64 + mi * 16 + g * 4 + r;
            float bv = b_def[co];
            unsigned short* dst = y1b + ((size_t)(b * 256 + co) << 10) + pos0;
            float s = 0.f, s2 = 0.f;
#pragma unroll
            for (int ni = 0; ni < 2; ++ni) {
                float v = acc[mi][ni][r] + bv;
                dst[wn * 32 + ni * 16 + l15] = f2bf(v);
                s += v;
                s2 += v * v;
            }
#pragma unroll
            for (int m = 8; m >= 1; m >>= 1) {
                s  += __shfl_xor(s, m, 64);
                s2 += __shfl_xor(s2, m, 64);
            }
            if (l15 == 0) {
                int col = wm * 64 + mi * 16 + g * 4 + r;
                sred[col * 2 + wn]  = s;
                s2red[col * 2 + wn] = s2;
            }
        }
    }
    __syncthreads();
    if (t < 128) {
        float s  = sred[t * 2] + sred[t * 2 + 1];
        float s2 = s2red[t * 2] + s2red[t * 2 + 1];
        int ch = m0 + t;
        pstats1[ch * 256 + nb] = s;
        pstats1[65536 + ch * 256 + nb] = s2;
    }
}

// ---------------- GEMM2: convT by parity, KSTEP=64, dbuf, 16x16 MFMA, bf16 outP, fused BN2 ----------------
__global__ __launch_bounds__(256) void k_gemm2(const unsigned short* __restrict__ A2,
                                               const unsigned short* __restrict__ y1T,
                                               unsigned short* __restrict__ outP,
                                               float* __restrict__ pstats2) {
    int nb = blockIdx.x, mb = blockIdx.y, p = blockIdx.z;
    int ph = p >> 1, pw = p & 1;
    int t = threadIdx.x;
    int lane = t & 63, wid = t >> 6;
    int wm = wid >> 1, wn = wid & 1;
    int l15 = lane & 15, g = lane >> 4;
    __shared__ __align__(16) unsigned short As[2][8192];
    __shared__ __align__(16) unsigned short Bs[2][8192];
    int m0 = mb * 128, n0 = nb * 128;
    int b = n0 >> 10, pos0 = n0 & 1023, oh0 = pos0 >> 5;

    int dtab[4];
#pragma unroll
    for (int tap = 0; tap < 4; ++tap) {
        int ty = tap >> 1, tx = tap & 1;
        int dy = ph ? (1 - ty) : (-ty);
        int dx = pw ? (1 - tx) : (-tx);
        dtab[tap] = (dy * 34 + dx) * 256;
    }
    const unsigned short* srcA[4];
    const unsigned short* srcB[4];
    int dstoff[4];
#pragma unroll
    for (int it = 0; it < 4; ++it) {
        int idx = t + it * 256;
        int r = idx >> 3, s8 = idx & 7, c = s8 ^ (r & 7);
        srcA[it] = A2 + (size_t)(p * 256 + m0 + r) * 1024 + c * 8;
        int ih = oh0 + (r >> 5) + 1;
        int iw = (r & 31) + 1;
        srcB[it] = y1T + ((size_t)(b * 34 + ih) * 34 + iw) * 256 + c * 8;
        dstoff[it] = idx * 8;
    }

    float4v acc[4][4];
    float4v z = {0.f, 0.f, 0.f, 0.f};
#pragma unroll
    for (int i = 0; i < 4; ++i)
#pragma unroll
        for (int j = 0; j < 4; ++j) acc[i][j] = z;

#pragma unroll
    for (int it = 0; it < 4; ++it) {
        stage1k(srcA[it], &As[0][dstoff[it]]);
        stage1k(srcB[it] + dtab[0], &Bs[0][dstoff[it]]);
    }
    __syncthreads();

#pragma unroll
    for (int step = 0; step < 16; ++step) {
        int cur = step & 1;
        if (step < 15) {
            int ns = step + 1;
            int tap = ns >> 2;
            int koff = ns * 64;
            int boff = dtab[tap] + (ns & 3) * 64;
#pragma unroll
            for (int it = 0; it < 4; ++it) {
                stage1k(srcA[it] + koff, &As[cur ^ 1][dstoff[it]]);
                stage1k(srcB[it] + boff, &Bs[cur ^ 1][dstoff[it]]);
            }
        }
        __builtin_amdgcn_s_setprio(1);
#pragma unroll
        for (int kk = 0; kk < 2; ++kk) {
            short8v a[4], bb[4];
#pragma unroll
            for (int mi = 0; mi < 4; ++mi) {
                int row = wm * 64 + mi * 16 + l15;
                int slot = ((kk << 2) + g) ^ (row & 7);
                a[mi] = *(const short8v*)((const char*)&As[cur][0] + row * 128 + slot * 16);
            }
#pragma unroll
            for (int ni = 0; ni < 4; ++ni) {
                int row = wn * 64 + ni * 16 + l15;
                int slot = ((kk << 2) + g) ^ (row & 7);
                bb[ni] = *(const short8v*)((const char*)&Bs[cur][0] + row * 128 + slot * 16);
            }
#pragma unroll
            for (int mi = 0; mi < 4; ++mi)
#pragma unroll
                for (int ni = 0; ni < 4; ++ni)
                    acc[mi][ni] = __builtin_amdgcn_mfma_f32_16x16x32_bf16(a[mi], bb[ni], acc[mi][ni], 0, 0, 0);
        }
        __builtin_amdgcn_s_setprio(0);
        __syncthreads();
    }
    // coalesced bf16 write to parity-planar outP
#pragma unroll
    for (int mi = 0; mi < 4; ++mi) {
#pragma unroll
        for (int r = 0; r < 4; ++r) {
            int co = m0 + wm * 64 + mi * 16 + g * 4 + r;
            unsigned short* dst = outP + ((size_t)((p * 16 + b) * 256 + co) << 10) + pos0;
#pragma unroll
            for (int ni = 0; ni < 4; ++ni)
                dst[wn * 64 + ni * 16 + l15] = f2bf(acc[mi][ni][r]);
        }
    }
    // fused BN2 partial stats (from fp32 accs)
    float* sred  = (float*)&As[0][0];
    float* s2red = sred + 256;
#pragma unroll
    for (int mi = 0; mi < 4; ++mi) {
#pragma unroll
        for (int r = 0; r < 4; ++r) {
            float s = 0.f, s2 = 0.f;
#pragma unroll
            for (int ni = 0; ni < 4; ++ni) {
                float v = acc[mi][ni][r];
                s += v;
                s2 += v * v;
            }
#pragma unroll
            for (int m = 8; m >= 1; m >>= 1) {
                s  += __shfl_xor(s, m, 64);
                s2 += __shfl_xor(s2, m, 64);
            }
            if (l15 == 0) {
                int col = wm * 64 + mi * 16 + g * 4 + r;
                sred[col * 2 + wn]  = s;
                s2red[col * 2 + wn] = s2;
            }
        }
    }
    __syncthreads();
    if (t < 128) {
        float s  = sred[t * 2] + sred[t * 2 + 1];
        float s2 = s2red[t * 2] + s2red[t * 2 + 1];
        int row = p * 128 + nb;
        int ch = m0 + t;
        pstats2[ch * 512 + row] = s;
        pstats2[131072 + ch * 512 + row] = s2;
    }
}

// ---------------- parallel BN finisher ----------------
__global__ __launch_bounds__(256) void k_bnfin_par(const float* __restrict__ pstats, int nparts,
                                                   float n,
                                                   float* __restrict__ mean, float* __restrict__ rstd) {
    int ch = blockIdx.x;
    int t = threadIdx.x;
    float s = 0.f, s2 = 0.f;
    for (int j = t; j < nparts; j += 256) {
        s  += pstats[ch * nparts + j];
        s2 += pstats[256 * nparts + ch * nparts + j];
    }
    __shared__ float rs[256], rs2[256];
    rs[t] = s; rs2[t] = s2;
    __syncthreads();
    for (int d = 128; d > 0; d >>= 1) {
        if (t < d) { rs[t] += rs[t + d]; rs2[t] += rs2[t + d]; }
        __syncthreads();
    }
    if (t == 0) {
        float m = rs[0] / n;
        float var = rs2[0] / n - m * m;
        mean[ch] = m;
        rstd[ch] = rsqrtf(var + 1e-5f);
    }
}

// ---------------- BN+SiLU on bf16 y1 -> channel-last padded bf16 y1T, halo zeroed ----------------
__global__ __launch_bounds__(256) void k_bnsilu_padT(const unsigned short* __restrict__ y1b,
                                                     const float* __restrict__ mean,
                                                     const float* __restrict__ rstd,
                                                     const float* __restrict__ gamma,
                                                     const float* __restrict__ beta,
                                                     unsigned short* __restrict__ y1T) {
    int py = blockIdx.x, cg = blockIdx.y, b = blockIdx.z;
    int c0 = cg * 32;
    int t = threadIdx.x;
    uint2 zz; zz.x = 0u; zz.y = 0u;
    if (py == 0 || py == 33) {
        for (int u = t; u < 272; u += 256) {
            int col = u >> 3, c4 = (u & 7) * 4;
            *(uint2*)&y1T[((size_t)(b * 34 + py) * 34 + col) * 256 + c0 + c4] = zz;
        }
        return;
    }
    __shared__ unsigned short tl[32][36];
    int iy = py - 1;
    {
        int c_l = t >> 3, px4 = (t & 7) * 4;
        int ch = c0 + c_l;
        float m = mean[ch], rs = rstd[ch], ga = gamma[ch], be = beta[ch];
        uint2 v = *(const uint2*)&y1b[(size_t)((b * 256 + ch) << 10) + (iy << 5) + px4];
        float f0 = __uint_as_float(v.x << 16), f1 = __uint_as_float(v.x & 0xFFFF0000u);
        float f2 = __uint_as_float(v.y << 16), f3 = __uint_as_float(v.y & 0xFFFF0000u);
        tl[c_l][px4 + 0] = f2bf(silu(ga * (f0 - m) * rs + be));
        tl[c_l][px4 + 1] = f2bf(silu(ga * (f1 - m) * rs + be));
        tl[c_l][px4 + 2] = f2bf(silu(ga * (f2 - m) * rs + be));
        tl[c_l][px4 + 3] = f2bf(silu(ga * (f3 - m) * rs + be));
    }
    __syncthreads();
    {
        int px = t >> 3, c4 = (t & 7) * 4;
        unsigned int s0 = tl[c4 + 0][px];
        unsigned int s1 = tl[c4 + 1][px];
        unsigned int s2 = tl[c4 + 2][px];
        unsigned int s3 = tl[c4 + 3][px];
        uint2 pk;
        pk.x = s0 | (s1 << 16);
        pk.y = s2 | (s3 << 16);
        *(uint2*)&y1T[((size_t)(b * 34 + py) * 34 + (px + 1)) * 256 + c0 + c4] = pk;
    }
    if (t < 16) {
        int col = (t >> 3) ? 33 : 0;
        int c4 = (t & 7) * 4;
        *(uint2*)&y1T[((size_t)(b * 34 + py) * 34 + col) * 256 + c0 + c4] = zz;
    }
}

// ---------------- final: BN+SiLU + parity interleave (bf16 outP) -> out ----------------
__global__ __launch_bounds__(256) void k_bnsilu_out(const unsigned short* __restrict__ outP,
                                                    const float* __restrict__ mean,
                                                    const float* __restrict__ rstd,
                                                    const float* __restrict__ gamma,
                                                    const float* __restrict__ beta,
                                                    float* __restrict__ out) {
    unsigned int i = blockIdx.x * 256 + threadIdx.x;
    int ow4 = i & 15;
    int oh = (i >> 4) & 63;
    int co = (i >> 10) & 255;
    int b  = i >> 18;
    int p0 = (oh & 1) * 2;
    int pos = ((oh >> 1) << 5) + ow4 * 2;
    const unsigned short* pl0 = outP + ((size_t)((p0 * 16 + b) * 256 + co) << 10) + pos;
    const unsigned short* pl1 = pl0 + ((size_t)16 * 256 << 10);
    unsigned int ue = *(const unsigned int*)pl0;
    unsigned int uo = *(const unsigned int*)pl1;
    float ex = __uint_as_float(ue << 16), ey = __uint_as_float(ue & 0xFFFF0000u);
    float ox = __uint_as_float(uo << 16), oy = __uint_as_float(uo & 0xFFFF0000u);
    float m = mean[co], rs = rstd[co], ga = gamma[co], be = beta[co];
    float4 v;
    v.x = silu(ga * (ex - m) * rs + be);
    v.y = silu(ga * (ox - m) * rs + be);
    v.z = silu(ga * (ey - m) * rs + be);
    v.w = silu(ga * (oy - m) * rs + be);
    *(float4*)&out[((size_t)(b * 256 + co) << 12) + (oh << 6) + ow4 * 4] = v;
}

extern "C" void kernel_launch(void* const* d_in, const int* in_sizes, int n_in,
                              void* d_out, int out_size, void* d_ws, size_t ws_size,
                              hipStream_t stream) {
    const float* x      = (const float*)d_in[0];
    const float* w_off  = (const float*)d_in[1];
    const float* b_off  = (const float*)d_in[2];
    const float* w_def  = (const float*)d_in[3];
    const float* b_def  = (const float*)d_in[4];
    const float* gamma1 = (const float*)d_in[5];
    const float* beta1  = (const float*)d_in[6];
    const float* w_dc   = (const float*)d_in[7];
    const float* gamma2 = (const float*)d_in[8];
    const float* beta2  = (const float*)d_in[9];
    float* out = (float*)d_out;

    char* base = (char*)d_ws;
    unsigned short* S    = (unsigned short*)base;                 // 75,497,472 B (dead after gemm1)
    unsigned short* y1b  = (unsigned short*)(base + 75497472);    //  8,388,608 B (bf16)
    unsigned short* y1T  = (unsigned short*)(base + 92274688);    //  9,469,952 B (padded ch-last)
    unsigned short* A1   = (unsigned short*)(base + 101744640);   //  1,179,648 B
    unsigned short* A2   = (unsigned short*)(base + 102924288);   //  2,097,152 B
    float*          off  = (float*)(base + 105021440);            //  1,179,648 B
    float*          stats = (float*)(base + 106201088);           //  1,024 B
    float* mean1 = stats, *rstd1 = stats + 256, *mean2 = stats + 512, *rstd2 = stats + 768;
    float* pstats1 = off;
    float* pstats2 = off;
    unsigned short* xT    = (unsigned short*)base;                //  8,388,608 B (dead after off_gemm)
    unsigned short* A2off = (unsigned short*)(base + 8388608);    //    147,456 B
    unsigned short* outP = (unsigned short*)base;  // 33,554,432 B, aliases S after gemm1

    k_prep_all<<<10784, 256, 0, stream>>>(w_def, w_dc, w_off, x, A1, A2, A2off, xT);
    k_off_gemm<<<dim3(16, 16), 256, 0, stream>>>(A2off, xT, b_off, off);
    k_sample<<<dim3(32, 16, 2), 576, 0, stream>>>(x, off, S);
    k_gemm1<<<dim3(256, 2), 256, 0, stream>>>(A1, S, b_def, y1b, pstats1);
    k_bnfin_par<<<256, 256, 0, stream>>>(pstats1, 256, 16384.f, mean1, rstd1);
    k_bnsilu_padT<<<dim3(34, 8, 16), 256, 0, stream>>>(y1b, mean1, rstd1, gamma1, beta1, y1T);
    k_gemm2<<<dim3(128, 2, 4), 256, 0, stream>>>(A2, y1T, outP, pstats2);
    k_bnfin_par<<<256, 256, 0, stream>>>(pstats2, 512, 65536.f, mean2, rstd2);
    k_bnsilu_out<<<16384, 256, 0, stream>>>(outP, mean2, rstd2, gamma2, beta2, out);
}

// Round 14
// 184.046 us; speedup vs baseline: 1.0805x; 1.0034x over previous
//
#include <hip/hip_runtime.h>
#include <math.h>

#ifdef __has_builtin
#if __has_builtin(__builtin_amdgcn_global_load_lds)
#define HAS_GLL 1
#endif
#endif
#ifndef HAS_GLL
#define HAS_GLL 0
#endif

typedef __attribute__((ext_vector_type(8))) short short8v;
typedef __attribute__((ext_vector_type(4))) float float4v;

__device__ __forceinline__ unsigned short f2bf(float f) {
    unsigned int u = __float_as_uint(f);
    u += 0x7fffu + ((u >> 16) & 1u);
    return (unsigned short)(u >> 16);
}

__device__ __forceinline__ float silu(float y) { return y / (1.f + expf(-y)); }

// wave stages 1KB into LDS: lane i -> ldsbase + 16*i, from per-lane gsrc (16B each)
__device__ __forceinline__ void stage1k(const void* gsrc, void* ldsbase) {
#if HAS_GLL
    __builtin_amdgcn_global_load_lds((const __attribute__((address_space(1))) unsigned int*)gsrc,
                                     (__attribute__((address_space(3))) unsigned int*)ldsbase,
                                     16, 0, 0);
#else
    int lane = threadIdx.x & 63;
    *(float4*)((char*)ldsbase + lane * 16) = *(const float4*)gsrc;
#endif
}

// ---------------- merged prep: A2 | A1 | A2off | xT ----------------
__global__ __launch_bounds__(256) void k_prep_all(const float* __restrict__ w_def,
                                                  const float* __restrict__ w_dc,
                                                  const float* __restrict__ w_off,
                                                  const float* __restrict__ x,
                                                  unsigned short* __restrict__ A1,
                                                  unsigned short* __restrict__ A2,
                                                  unsigned short* __restrict__ A2off,
                                                  unsigned short* __restrict__ xT) {
    int blk = blockIdx.x;
    int t = threadIdx.x;
    __shared__ unsigned short tl[32][36];
    if (blk < 4096) {
        int i = blk * 256 + t;
        int ci = i & 255;
        int tq = (i >> 8) & 3;
        int co = (i >> 10) & 255;
        int p  = i >> 18;
        int ph = p >> 1, pw = p & 1;
        int ty = tq >> 1, tx = tq & 1;
        int kh = 2 * ty + 1 - ph;
        int kw = 2 * tx + 1 - pw;
        A2[i] = f2bf(w_dc[((ci * 256 + co) * 4 + kh) * 4 + kw]);
    } else if (blk < 6400) {
        int i = (blk - 4096) * 256 + t;
        A1[i] = f2bf(w_def[i]);
    } else if (blk < 6688) {
        int i = (blk - 6400) * 256 + t;
        int slot = i & 31;
        int oc = (i >> 5) & 31;
        int rest = i >> 10;
        int tap = rest % 9;
        int cc8 = rest / 9;
        int cgrp = (slot >> 3) ^ ((oc >> 1) & 3);
        int c = cc8 * 32 + (cgrp << 3) + (slot & 7);
        unsigned short v = 0;
        if (oc < 18) v = f2bf(w_off[(size_t)oc * 2304 + c * 9 + tap]);
        A2off[i] = v;
    } else {
        int blk2 = blk - 6688;
        int hw0 = (blk2 & 31) * 32;
        int c0 = ((blk2 >> 5) & 7) * 32;
        int b = blk2 >> 8;
        {
            int c_l = t >> 3, w4 = (t & 7) * 4;
            float4 v = *(const float4*)&x[(size_t)((b * 256 + c0 + c_l) * 1024) + hw0 + w4];
            tl[c_l][w4 + 0] = f2bf(v.x);
            tl[c_l][w4 + 1] = f2bf(v.y);
            tl[c_l][w4 + 2] = f2bf(v.z);
            tl[c_l][w4 + 3] = f2bf(v.w);
        }
        __syncthreads();
        {
            int hw_l = t >> 3, c4 = (t & 7) * 4;
            unsigned int s0 = tl[c4 + 0][hw_l];
            unsigned int s1 = tl[c4 + 1][hw_l];
            unsigned int s2 = tl[c4 + 2][hw_l];
            unsigned int s3 = tl[c4 + 3][hw_l];
            uint2 pk;
            pk.x = s0 | (s1 << 16);
            pk.y = s2 | (s3 << 16);
            *(uint2*)&xT[(size_t)((b * 1024 + hw0 + hw_l) * 256) + c0 + c4] = pk;
        }
    }
}

// ---------------- offset conv as MFMA GEMM ----------------
__global__ __launch_bounds__(256) void k_off_gemm(const unsigned short* __restrict__ A2off,
                                                  const unsigned short* __restrict__ xT,
                                                  const float* __restrict__ b_off,
                                                  float* __restrict__ off) {
    int hp = blockIdx.x, b = blockIdx.y;
    int h0 = hp * 2;
    int t = threadIdx.x;
    int lane = t & 63, wid = t >> 6;
    int l15 = lane & 15, g = lane >> 4;
    int swg = (l15 >> 1) & 3;
    __shared__ __align__(16) unsigned short As[9 * 32 * 32];
    __shared__ __align__(16) unsigned short Bsx[4 * 34 * 32];
    float4v acc[2];
    float4v z = {0.f, 0.f, 0.f, 0.f};
    acc[0] = z; acc[1] = z;

    int pos = wid * 16 + l15;
    int py = pos >> 5, px = pos & 31;

    for (int cc8 = 0; cc8 < 8; ++cc8) {
        __syncthreads();
        for (int idx = t; idx < 1152; idx += 256)
            stage1k(A2off + (size_t)cc8 * 9216 + idx * 8, (char*)As + idx * 16);
        for (int idx = t; idx < 544; idx += 256) {
            int r = idx / 136;
            int rem = idx - r * 136;
            int col = rem >> 2;
            int sgrp = rem & 3;
            int grp = sgrp ^ ((col >> 1) & 3);
            int h = h0 - 1 + r;
            int w = col - 1;
            uint4 v = {0u, 0u, 0u, 0u};
            if (h >= 0 && h < 32 && w >= 0 && w < 32)
                v = *(const uint4*)&xT[(size_t)((b * 1024 + h * 32 + w) * 256) + cc8 * 32 + grp * 8];
            *(uint4*)((char*)Bsx + ((r * 34 + col) << 6) + (sgrp << 4)) = v;
        }
        __syncthreads();
#pragma unroll
        for (int tap = 0; tap < 9; ++tap) {
            int ky = tap / 3, kx = tap - ky * 3;
            int col = px + kx;
            int rowr = py + ky;
            short8v bbf = *(const short8v*)((const char*)Bsx + ((rowr * 34 + col) << 6) +
                                            ((g ^ ((col >> 1) & 3)) << 4));
            short8v a0 = *(const short8v*)((const char*)As + tap * 2048 + l15 * 64 + ((g ^ swg) << 4));
            short8v a1 = *(const short8v*)((const char*)As + tap * 2048 + (16 + l15) * 64 + ((g ^ swg) << 4));
            acc[0] = __builtin_amdgcn_mfma_f32_16x16x32_bf16(a0, bbf, acc[0], 0, 0, 0);
            acc[1] = __builtin_amdgcn_mfma_f32_16x16x32_bf16(a1, bbf, acc[1], 0, 0, 0);
        }
    }
    int h = h0 + py;
#pragma unroll
    for (int r = 0; r < 4; ++r) {
        int oc = g * 4 + r;
        off[((size_t)(b * 18 + oc) << 10) + (h << 5) + px] = acc[0][r] + b_off[oc];
    }
    if (g == 0) {
#pragma unroll
        for (int r = 0; r < 2; ++r) {
            int oc = 16 + r;
            off[((size_t)(b * 18 + oc) << 10) + (h << 5) + px] = acc[1][r] + b_off[oc];
        }
    }
}

// ---------------- bilinear sampler ----------------
__global__ __launch_bounds__(576) void k_sample(const float* __restrict__ x,
                                                const float* __restrict__ off,
                                                unsigned short* __restrict__ S) {
    int cg = blockIdx.x, b = blockIdx.y, half = blockIdx.z;
    int cbase = cg * 8;
    int t = threadIdx.x;
    int k = t >> 6, lane = t & 63;
    __shared__ __align__(16) unsigned int xpl[4 * 1156];
    __shared__ __align__(16) unsigned short sS[72 * 66];

    for (int u = t; u < 1024; u += 576) {
        int p = u >> 8, row = (u >> 3) & 31, cq = (u & 7) << 2;
        const float* src0 = x + ((size_t)(b * 256 + cbase + 2 * p) << 10) + (row << 5) + cq;
        float4 a = *(const float4*)src0;
        float4 c = *(const float4*)(src0 + 1024);
        uint4 pk;
        pk.x = (unsigned int)f2bf(a.x) | ((unsigned int)f2bf(c.x) << 16);
        pk.y = (unsigned int)f2bf(a.y) | ((unsigned int)f2bf(c.y) << 16);
        pk.z = (unsigned int)f2bf(a.z) | ((unsigned int)f2bf(c.z) << 16);
        pk.w = (unsigned int)f2bf(a.w) | ((unsigned int)f2bf(c.w) << 16);
        *(uint4*)&xpl[p * 1156 + row * 36 + cq] = pk;
    }

    int wr_row = t / 9, wr_q = t - wr_row * 9;
    const float* offk0 = off + ((size_t)(b * 18 + 2 * k) << 10);
    const float* offk1 = off + ((size_t)(b * 18 + 2 * k + 1) << 10);
    int ky = k / 3 - 1, kx = k % 3 - 1;
    __syncthreads();

    for (int ci = 0; ci < 8; ++ci) {
        int chunk = half * 8 + ci;
        int pos = chunk * 64 + lane;
        int h = pos >> 5, w = pos & 31;
        float dy = offk0[pos];
        float dx = offk1[pos];
        float py = (float)(h + ky) + dy;
        float px = (float)(w + kx) + dx;
        float fy = floorf(py), fx = floorf(px);
        int y0i = (int)fy, x0i = (int)fx;
        float wy = py - fy, wxf = px - fx;
        float vy0 = (y0i >= 0 && y0i < 32) ? 1.f : 0.f;
        float vy1 = (y0i >= -1 && y0i < 31) ? 1.f : 0.f;
        float vx0 = (x0i >= 0 && x0i < 32) ? 1.f : 0.f;
        float vx1 = (x0i >= -1 && x0i < 31) ? 1.f : 0.f;
        int y0c = min(max(y0i, 0), 31), y1c = min(max(y0i + 1, 0), 31);
        int x0c = min(max(x0i, 0), 31), x1c = min(max(x0i + 1, 0), 31);
        float w00 = (1.f - wy) * (1.f - wxf) * vy0 * vx0;
        float w01 = (1.f - wy) * wxf * vy0 * vx1;
        float w10 = wy * (1.f - wxf) * vy1 * vx0;
        float w11 = wy * wxf * vy1 * vx1;
        int a00 = y0c * 36 + x0c, a01 = y0c * 36 + x1c;
        int a10 = y1c * 36 + x0c, a11 = y1c * 36 + x1c;
#pragma unroll
        for (int p = 0; p < 4; ++p) {
            const unsigned int* pl = xpl + p * 1156;
            unsigned int c00 = pl[a00], c01 = pl[a01], c10 = pl[a10], c11 = pl[a11];
            float e00 = __uint_as_float(c00 << 16), o00 = __uint_as_float(c00 & 0xFFFF0000u);
            float e01 = __uint_as_float(c01 << 16), o01 = __uint_as_float(c01 & 0xFFFF0000u);
            float e10 = __uint_as_float(c10 << 16), o10 = __uint_as_float(c10 & 0xFFFF0000u);
            float e11 = __uint_as_float(c11 << 16), o11 = __uint_as_float(c11 & 0xFFFF0000u);
            float ve = w00 * e00 + w01 * e01 + w10 * e10 + w11 * e11;
            float vo = w00 * o00 + w01 * o01 + w10 * o10 + w11 * o11;
            sS[((2 * p) * 9 + k) * 66 + lane] = f2bf(ve);
            sS[((2 * p + 1) * 9 + k) * 66 + lane] = f2bf(vo);
        }
        __syncthreads();
        {
            int basekc = wr_q * 8;
            unsigned int s0 = sS[(basekc + 0) * 66 + wr_row];
            unsigned int s1 = sS[(basekc + 1) * 66 + wr_row];
            unsigned int s2 = sS[(basekc + 2) * 66 + wr_row];
            unsigned int s3 = sS[(basekc + 3) * 66 + wr_row];
            unsigned int s4 = sS[(basekc + 4) * 66 + wr_row];
            unsigned int s5 = sS[(basekc + 5) * 66 + wr_row];
            unsigned int s6 = sS[(basekc + 6) * 66 + wr_row];
            unsigned int s7 = sS[(basekc + 7) * 66 + wr_row];
            uint4 qv;
            qv.x = s0 | (s1 << 16);
            qv.y = s2 | (s3 << 16);
            qv.z = s4 | (s5 << 16);
            qv.w = s6 | (s7 << 16);
            *(uint4*)(S + (size_t)(b * 1024 + chunk * 64 + wr_row) * 2304 + cg * 72 + wr_q * 8) = qv;
        }
        __syncthreads();
    }
}

// ---------------- GEMM1: BM=128, BN=64, KSTEP=64, counted-vmcnt dbuf, fused BN1, bf16 y1 ----------------
// grid (256 nb, 2 mb), 256 threads
__global__ __launch_bounds__(256) void k_gemm1(const unsigned short* __restrict__ A1,
                                               const unsigned short* __restrict__ S,
                                               const float* __restrict__ b_def,
                                               unsigned short* __restrict__ y1b,
                                               float* __restrict__ pstats1) {
    int nb = blockIdx.x, mb = blockIdx.y;
    int t = threadIdx.x;
    int lane = t & 63, wid = t >> 6;
    int wm = wid >> 1, wn = wid & 1;
    int l15 = lane & 15, g = lane >> 4;
    __shared__ __align__(16) unsigned short As[2][8192];  // 128 x 64
    __shared__ __align__(16) unsigned short Bs[2][4096];  // 64 x 64
    int m0 = mb * 128, n0 = nb * 64;
    int b = n0 >> 10, pos0 = n0 & 1023;

    const unsigned short* srcA[4];
    int dA[4];
    const unsigned short* srcB[2];
    int dB[2];
#pragma unroll
    for (int it = 0; it < 4; ++it) {
        int idx = t + it * 256;
        int r = idx >> 3, s8 = idx & 7, c = s8 ^ (r & 7);
        srcA[it] = A1 + (size_t)(m0 + r) * 2304 + c * 8;
        dA[it] = idx * 8;
    }
#pragma unroll
    for (int it = 0; it < 2; ++it) {
        int idx = t + it * 256;
        int r = idx >> 3, s8 = idx & 7, c = s8 ^ (r & 7);
        srcB[it] = S + (size_t)(n0 + r) * 2304 + c * 8;
        dB[it] = idx * 8;
    }

    float4v acc[4][2];
    float4v z = {0.f, 0.f, 0.f, 0.f};
#pragma unroll
    for (int i = 0; i < 4; ++i) { acc[i][0] = z; acc[i][1] = z; }

#pragma unroll
    for (int it = 0; it < 4; ++it) stage1k(srcA[it], &As[0][dA[it]]);
#pragma unroll
    for (int it = 0; it < 2; ++it) stage1k(srcB[it], &Bs[0][dB[it]]);

#define G1_COMPUTE(CUR)                                                                     \
    {                                                                                       \
        __builtin_amdgcn_s_setprio(1);                                                      \
        _Pragma("unroll")                                                                   \
        for (int kk = 0; kk < 2; ++kk) {                                                    \
            short8v a[4], bb[2];                                                            \
            _Pragma("unroll")                                                               \
            for (int mi = 0; mi < 4; ++mi) {                                                \
                int row = wm * 64 + mi * 16 + l15;                                          \
                int slot = ((kk << 2) + g) ^ (row & 7);                                     \
                a[mi] = *(const short8v*)((const char*)&As[CUR][0] + row * 128 + slot * 16);\
            }                                                                               \
            _Pragma("unroll")                                                               \
            for (int ni = 0; ni < 2; ++ni) {                                                \
                int row = wn * 32 + ni * 16 + l15;                                          \
                int slot = ((kk << 2) + g) ^ (row & 7);                                     \
                bb[ni] = *(const short8v*)((const char*)&Bs[CUR][0] + row * 128 + slot * 16);\
            }                                                                               \
            _Pragma("unroll")                                                               \
            for (int mi = 0; mi < 4; ++mi)                                                  \
                _Pragma("unroll")                                                           \
                for (int ni = 0; ni < 2; ++ni)                                              \
                    acc[mi][ni] = __builtin_amdgcn_mfma_f32_16x16x32_bf16(a[mi], bb[ni],    \
                                                                          acc[mi][ni], 0, 0, 0);\
        }                                                                                   \
        __builtin_amdgcn_s_setprio(0);                                                      \
    }

    for (int step = 0; step < 35; ++step) {
        int cur = step & 1;
        int koff = (step + 1) * 64;
#pragma unroll
        for (int it = 0; it < 4; ++it) stage1k(srcA[it] + koff, &As[cur ^ 1][dA[it]]);
#pragma unroll
        for (int it = 0; it < 2; ++it) stage1k(srcB[it] + koff, &Bs[cur ^ 1][dB[it]]);
        asm volatile("s_waitcnt vmcnt(6)" ::: "memory");
        __builtin_amdgcn_s_barrier();
        asm volatile("" ::: "memory");
        if (cur == 0) { G1_COMPUTE(0); } else { G1_COMPUTE(1); }
        asm volatile("" ::: "memory");
        __builtin_amdgcn_s_barrier();
    }
    asm volatile("s_waitcnt vmcnt(0)" ::: "memory");
    __builtin_amdgcn_s_barrier();
    asm volatile("" ::: "memory");
    G1_COMPUTE(1)  // step 35: cur = 1
#undef G1_COMPUTE

    // epilogue: bias + bf16 write + BN1 partial stats
    float* sred  = (float*)&As[0][0];  // [128][2]
    float* s2red = sred + 256;
#pragma unroll
    for (int mi = 0; mi < 4; ++mi) {
#pragma unroll
        for (int r = 0; r < 4; ++r) {
            int co = m0 + wm * 64 + mi * 16 + g * 4 + r;
            float bv = b_def[co];
            unsigned short* dst = y1b + ((size_t)(b * 256 + co) << 10) + pos0;
            float s = 0.f, s2 = 0.f;
#pragma unroll
            for (int ni = 0; ni < 2; ++ni) {
                float v = acc[mi][ni][r] + bv;
                dst[wn * 32 + ni * 16 + l15] = f2bf(v);
                s += v;
                s2 += v * v;
            }
#pragma unroll
            for (int m = 8; m >= 1; m >>= 1) {
                s  += __shfl_xor(s, m, 64);
                s2 += __shfl_xor(s2, m, 64);
            }
            if (l15 == 0) {
                int col = wm * 64 + mi * 16 + g * 4 + r;
                sred[col * 2 + wn]  = s;
                s2red[col * 2 + wn] = s2;
            }
        }
    }
    __syncthreads();
    if (t < 128) {
        float s  = sred[t * 2] + sred[t * 2 + 1];
        float s2 = s2red[t * 2] + s2red[t * 2 + 1];
        int ch = m0 + t;
        pstats1[ch * 256 + nb] = s;
        pstats1[65536 + ch * 256 + nb] = s2;
    }
}

// ---------------- GEMM2: convT by parity, KSTEP=64, counted-vmcnt dbuf, bf16 outP, fused BN2 ----------------
__global__ __launch_bounds__(256) void k_gemm2(const unsigned short* __restrict__ A2,
                                               const unsigned short* __restrict__ y1T,
                                               unsigned short* __restrict__ outP,
                                               float* __restrict__ pstats2) {
    int nb = blockIdx.x, mb = blockIdx.y, p = blockIdx.z;
    int ph = p >> 1, pw = p & 1;
    int t = threadIdx.x;
    int lane = t & 63, wid = t >> 6;
    int wm = wid >> 1, wn = wid & 1;
    int l15 = lane & 15, g = lane >> 4;
    __shared__ __align__(16) unsigned short As[2][8192];
    __shared__ __align__(16) unsigned short Bs[2][8192];
    int m0 = mb * 128, n0 = nb * 128;
    int b = n0 >> 10, pos0 = n0 & 1023, oh0 = pos0 >> 5;

    int dtab[4];
#pragma unroll
    for (int tap = 0; tap < 4; ++tap) {
        int ty = tap >> 1, tx = tap & 1;
        int dy = ph ? (1 - ty) : (-ty);
        int dx = pw ? (1 - tx) : (-tx);
        dtab[tap] = (dy * 34 + dx) * 256;
    }
    const unsigned short* srcA[4];
    const unsigned short* srcB[4];
    int dstoff[4];
#pragma unroll
    for (int it = 0; it < 4; ++it) {
        int idx = t + it * 256;
        int r = idx >> 3, s8 = idx & 7, c = s8 ^ (r & 7);
        srcA[it] = A2 + (size_t)(p * 256 + m0 + r) * 1024 + c * 8;
        int ih = oh0 + (r >> 5) + 1;
        int iw = (r & 31) + 1;
        srcB[it] = y1T + ((size_t)(b * 34 + ih) * 34 + iw) * 256 + c * 8;
        dstoff[it] = idx * 8;
    }

    float4v acc[4][4];
    float4v z = {0.f, 0.f, 0.f, 0.f};
#pragma unroll
    for (int i = 0; i < 4; ++i)
#pragma unroll
        for (int j = 0; j < 4; ++j) acc[i][j] = z;

#pragma unroll
    for (int it = 0; it < 4; ++it) {
        stage1k(srcA[it], &As[0][dstoff[it]]);
        stage1k(srcB[it] + dtab[0], &Bs[0][dstoff[it]]);
    }

#define G2_COMPUTE(CUR)                                                                     \
    {                                                                                       \
        __builtin_amdgcn_s_setprio(1);                                                      \
        _Pragma("unroll")                                                                   \
        for (int kk = 0; kk < 2; ++kk) {                                                    \
            short8v a[4], bb[4];                                                            \
            _Pragma("unroll")                                                               \
            for (int mi = 0; mi < 4; ++mi) {                                                \
                int row = wm * 64 + mi * 16 + l15;                                          \
                int slot = ((kk << 2) + g) ^ (row & 7);                                     \
                a[mi] = *(const short8v*)((const char*)&As[CUR][0] + row * 128 + slot * 16);\
            }                                                                               \
            _Pragma("unroll")                                                               \
            for (int ni = 0; ni < 4; ++ni) {                                                \
                int row = wn * 64 + ni * 16 + l15;                                          \
                int slot = ((kk << 2) + g) ^ (row & 7);                                     \
                bb[ni] = *(const short8v*)((const char*)&Bs[CUR][0] + row * 128 + slot * 16);\
            }                                                                               \
            _Pragma("unroll")                                                               \
            for (int mi = 0; mi < 4; ++mi)                                                  \
                _Pragma("unroll")                                                           \
                for (int ni = 0; ni < 4; ++ni)                                              \
                    acc[mi][ni] = __builtin_amdgcn_mfma_f32_16x16x32_bf16(a[mi], bb[ni],    \
                                                                          acc[mi][ni], 0, 0, 0);\
        }                                                                                   \
        __builtin_amdgcn_s_setprio(0);                                                      \
    }

#pragma unroll
    for (int step = 0; step < 15; ++step) {
        int cur = step & 1;
        int ns = step + 1;
        int tap = ns >> 2;
        int koff = ns * 64;
        int boff = dtab[tap] + (ns & 3) * 64;
#pragma unroll
        for (int it = 0; it < 4; ++it) {
            stage1k(srcA[it] + koff, &As[cur ^ 1][dstoff[it]]);
            stage1k(srcB[it] + boff, &Bs[cur ^ 1][dstoff[it]]);
        }
        asm volatile("s_waitcnt vmcnt(8)" ::: "memory");
        __builtin_amdgcn_s_barrier();
        asm volatile("" ::: "memory");
        if (cur == 0) { G2_COMPUTE(0); } else { G2_COMPUTE(1); }
        asm volatile("" ::: "memory");
        __builtin_amdgcn_s_barrier();
    }
    asm volatile("s_waitcnt vmcnt(0)" ::: "memory");
    __builtin_amdgcn_s_barrier();
    asm volatile("" ::: "memory");
    G2_COMPUTE(1)  // step 15: cur = 1
#undef G2_COMPUTE

    // coalesced bf16 write to parity-planar outP
#pragma unroll
    for (int mi = 0; mi < 4; ++mi) {
#pragma unroll
        for (int r = 0; r < 4; ++r) {
            int co = m0 + wm * 64 + mi * 16 + g * 4 + r;
            unsigned short* dst = outP + ((size_t)((p * 16 + b) * 256 + co) << 10) + pos0;
#pragma unroll
            for (int ni = 0; ni < 4; ++ni)
                dst[wn * 64 + ni * 16 + l15] = f2bf(acc[mi][ni][r]);
        }
    }
    // fused BN2 partial stats (from fp32 accs)
    float* sred  = (float*)&As[0][0];
    float* s2red = sred + 256;
#pragma unroll
    for (int mi = 0; mi < 4; ++mi) {
#pragma unroll
        for (int r = 0; r < 4; ++r) {
            float s = 0.f, s2 = 0.f;
#pragma unroll
            for (int ni = 0; ni < 4; ++ni) {
                float v = acc[mi][ni][r];
                s += v;
                s2 += v * v;
            }
#pragma unroll
            for (int m = 8; m >= 1; m >>= 1) {
                s  += __shfl_xor(s, m, 64);
                s2 += __shfl_xor(s2, m, 64);
            }
            if (l15 == 0) {
                int col = wm * 64 + mi * 16 + g * 4 + r;
                sred[col * 2 + wn]  = s;
                s2red[col * 2 + wn] = s2;
            }
        }
    }
    __syncthreads();
    if (t < 128) {
        float s  = sred[t * 2] + sred[t * 2 + 1];
        float s2 = s2red[t * 2] + s2red[t * 2 + 1];
        int row = p * 128 + nb;
        int ch = m0 + t;
        pstats2[ch * 512 + row] = s;
        pstats2[131072 + ch * 512 + row] = s2;
    }
}

// ---------------- parallel BN finisher ----------------
__global__ __launch_bounds__(256) void k_bnfin_par(const float* __restrict__ pstats, int nparts,
                                                   float n,
                                                   float* __restrict__ mean, float* __restrict__ rstd) {
    int ch = blockIdx.x;
    int t = threadIdx.x;
    float s = 0.f, s2 = 0.f;
    for (int j = t; j < nparts; j += 256) {
        s  += pstats[ch * nparts + j];
        s2 += pstats[256 * nparts + ch * nparts + j];
    }
    __shared__ float rs[256], rs2[256];
    rs[t] = s; rs2[t] = s2;
    __syncthreads();
    for (int d = 128; d > 0; d >>= 1) {
        if (t < d) { rs[t] += rs[t + d]; rs2[t] += rs2[t + d]; }
        __syncthreads();
    }
    if (t == 0) {
        float m = rs[0] / n;
        float var = rs2[0] / n - m * m;
        mean[ch] = m;
        rstd[ch] = rsqrtf(var + 1e-5f);
    }
}

// ---------------- BN+SiLU on bf16 y1 -> channel-last padded bf16 y1T, halo zeroed ----------------
__global__ __launch_bounds__(256) void k_bnsilu_padT(const unsigned short* __restrict__ y1b,
                                                     const float* __restrict__ mean,
                                                     const float* __restrict__ rstd,
                                                     const float* __restrict__ gamma,
                                                     const float* __restrict__ beta,
                                                     unsigned short* __restrict__ y1T) {
    int py = blockIdx.x, cg = blockIdx.y, b = blockIdx.z;
    int c0 = cg * 32;
    int t = threadIdx.x;
    uint2 zz; zz.x = 0u; zz.y = 0u;
    if (py == 0 || py == 33) {
        for (int u = t; u < 272; u += 256) {
            int col = u >> 3, c4 = (u & 7) * 4;
            *(uint2*)&y1T[((size_t)(b * 34 + py) * 34 + col) * 256 + c0 + c4] = zz;
        }
        return;
    }
    __shared__ unsigned short tl[32][36];
    int iy = py - 1;
    {
        int c_l = t >> 3, px4 = (t & 7) * 4;
        int ch = c0 + c_l;
        float m = mean[ch], rs = rstd[ch], ga = gamma[ch], be = beta[ch];
        uint2 v = *(const uint2*)&y1b[(size_t)((b * 256 + ch) << 10) + (iy << 5) + px4];
        float f0 = __uint_as_float(v.x << 16), f1 = __uint_as_float(v.x & 0xFFFF0000u);
        float f2 = __uint_as_float(v.y << 16), f3 = __uint_as_float(v.y & 0xFFFF0000u);
        tl[c_l][px4 + 0] = f2bf(silu(ga * (f0 - m) * rs + be));
        tl[c_l][px4 + 1] = f2bf(silu(ga * (f1 - m) * rs + be));
        tl[c_l][px4 + 2] = f2bf(silu(ga * (f2 - m) * rs + be));
        tl[c_l][px4 + 3] = f2bf(silu(ga * (f3 - m) * rs + be));
    }
    __syncthreads();
    {
        int px = t >> 3, c4 = (t & 7) * 4;
        unsigned int s0 = tl[c4 + 0][px];
        unsigned int s1 = tl[c4 + 1][px];
        unsigned int s2 = tl[c4 + 2][px];
        unsigned int s3 = tl[c4 + 3][px];
        uint2 pk;
        pk.x = s0 | (s1 << 16);
        pk.y = s2 | (s3 << 16);
        *(uint2*)&y1T[((size_t)(b * 34 + py) * 34 + (px + 1)) * 256 + c0 + c4] = pk;
    }
    if (t < 16) {
        int col = (t >> 3) ? 33 : 0;
        int c4 = (t & 7) * 4;
        *(uint2*)&y1T[((size_t)(b * 34 + py) * 34 + col) * 256 + c0 + c4] = zz;
    }
}

// ---------------- final: BN+SiLU + parity interleave (bf16 outP) -> out ----------------
__global__ __launch_bounds__(256) void k_bnsilu_out(const unsigned short* __restrict__ outP,
                                                    const float* __restrict__ mean,
                                                    const float* __restrict__ rstd,
                                                    const float* __restrict__ gamma,
                                                    const float* __restrict__ beta,
                                                    float* __restrict__ out) {
    unsigned int i = blockIdx.x * 256 + threadIdx.x;
    int ow4 = i & 15;
    int oh = (i >> 4) & 63;
    int co = (i >> 10) & 255;
    int b  = i >> 18;
    int p0 = (oh & 1) * 2;
    int pos = ((oh >> 1) << 5) + ow4 * 2;
    const unsigned short* pl0 = outP + ((size_t)((p0 * 16 + b) * 256 + co) << 10) + pos;
    const unsigned short* pl1 = pl0 + ((size_t)16 * 256 << 10);
    unsigned int ue = *(const unsigned int*)pl0;
    unsigned int uo = *(const unsigned int*)pl1;
    float ex = __uint_as_float(ue << 16), ey = __uint_as_float(ue & 0xFFFF0000u);
    float ox = __uint_as_float(uo << 16), oy = __uint_as_float(uo & 0xFFFF0000u);
    float m = mean[co], rs = rstd[co], ga = gamma[co], be = beta[co];
    float4 v;
    v.x = silu(ga * (ex - m) * rs + be);
    v.y = silu(ga * (ox - m) * rs + be);
    v.z = silu(ga * (ey - m) * rs + be);
    v.w = silu(ga * (oy - m) * rs + be);
    *(float4*)&out[((size_t)(b * 256 + co) << 12) + (oh << 6) + ow4 * 4] = v;
}

extern "C" void kernel_launch(void* const* d_in, const int* in_sizes, int n_in,
                              void* d_out, int out_size, void* d_ws, size_t ws_size,
                              hipStream_t stream) {
    const float* x      = (const float*)d_in[0];
    const float* w_off  = (const float*)d_in[1];
    const float* b_off  = (const float*)d_in[2];
    const float* w_def  = (const float*)d_in[3];
    const float* b_def  = (const float*)d_in[4];
    const float* gamma1 = (const float*)d_in[5];
    const float* beta1  = (const float*)d_in[6];
    const float* w_dc   = (const float*)d_in[7];
    const float* gamma2 = (const float*)d_in[8];
    const float* beta2  = (const float*)d_in[9];
    float* out = (float*)d_out;

    char* base = (char*)d_ws;
    unsigned short* S    = (unsigned short*)base;                 // 75,497,472 B (dead after gemm1)
    unsigned short* y1b  = (unsigned short*)(base + 75497472);    //  8,388,608 B (bf16)
    unsigned short* y1T  = (unsigned short*)(base + 92274688);    //  9,469,952 B (padded ch-last)
    unsigned short* A1   = (unsigned short*)(base + 101744640);   //  1,179,648 B
    unsigned short* A2   = (unsigned short*)(base + 102924288);   //  2,097,152 B
    float*          off  = (float*)(base + 105021440);            //  1,179,648 B
    float*          stats = (float*)(base + 106201088);           //  1,024 B
    float* mean1 = stats, *rstd1 = stats + 256, *mean2 = stats + 512, *rstd2 = stats + 768;
    float* pstats1 = off;
    float* pstats2 = off;
    unsigned short* xT    = (unsigned short*)base;                //  8,388,608 B (dead after off_gemm)
    unsigned short* A2off = (unsigned short*)(base + 8388608);    //    147,456 B
    unsigned short* outP = (unsigned short*)base;  // 33,554,432 B, aliases S after gemm1

    k_prep_all<<<10784, 256, 0, stream>>>(w_def, w_dc, w_off, x, A1, A2, A2off, xT);
    k_off_gemm<<<dim3(16, 16), 256, 0, stream>>>(A2off, xT, b_off, off);
    k_sample<<<dim3(32, 16, 2), 576, 0, stream>>>(x, off, S);
    k_gemm1<<<dim3(256, 2), 256, 0, stream>>>(A1, S, b_def, y1b, pstats1);
    k_bnfin_par<<<256, 256, 0, stream>>>(pstats1, 256, 16384.f, mean1, rstd1);
    k_bnsilu_padT<<<dim3(34, 8, 16), 256, 0, stream>>>(y1b, mean1, rstd1, gamma1, beta1, y1T);
    k_gemm2<<<dim3(128, 2, 4), 256, 0, stream>>>(A2, y1T, outP, pstats2);
    k_bnfin_par<<<256, 256, 0, stream>>>(pstats2, 512, 65536.f, mean2, rstd2);
    k_bnsilu_out<<<16384, 256, 0, stream>>>(outP, mean2, rstd2, gamma2, beta2, out);
}

// Round 15
// 182.633 us; speedup vs baseline: 1.0888x; 1.0077x over previous
//
#include <hip/hip_runtime.h>
#include <math.h>

#ifdef __has_builtin
#if __has_builtin(__builtin_amdgcn_global_load_lds)
#define HAS_GLL 1
#endif
#endif
#ifndef HAS_GLL
#define HAS_GLL 0
#endif

typedef __attribute__((ext_vector_type(8))) short short8v;
typedef __attribute__((ext_vector_type(4))) float float4v;

__device__ __forceinline__ unsigned short f2bf(float f) {
    unsigned int u = __float_as_uint(f);
    u += 0x7fffu + ((u >> 16) & 1u);
    return (unsigned short)(u >> 16);
}

__device__ __forceinline__ float silu(float y) { return y / (1.f + expf(-y)); }

// wave stages 1KB into LDS: lane i -> ldsbase + 16*i, from per-lane gsrc (16B each)
__device__ __forceinline__ void stage1k(const void* gsrc, void* ldsbase) {
#if HAS_GLL
    __builtin_amdgcn_global_load_lds((const __attribute__((address_space(1))) unsigned int*)gsrc,
                                     (__attribute__((address_space(3))) unsigned int*)ldsbase,
                                     16, 0, 0);
#else
    int lane = threadIdx.x & 63;
    *(float4*)((char*)ldsbase + lane * 16) = *(const float4*)gsrc;
#endif
}

// ---------------- merged prep: A2 | A1 | A2off | xT ----------------
__global__ __launch_bounds__(256) void k_prep_all(const float* __restrict__ w_def,
                                                  const float* __restrict__ w_dc,
                                                  const float* __restrict__ w_off,
                                                  const float* __restrict__ x,
                                                  unsigned short* __restrict__ A1,
                                                  unsigned short* __restrict__ A2,
                                                  unsigned short* __restrict__ A2off,
                                                  unsigned short* __restrict__ xT) {
    int blk = blockIdx.x;
    int t = threadIdx.x;
    __shared__ unsigned short tl[32][36];
    if (blk < 4096) {
        int i = blk * 256 + t;
        int ci = i & 255;
        int tq = (i >> 8) & 3;
        int co = (i >> 10) & 255;
        int p  = i >> 18;
        int ph = p >> 1, pw = p & 1;
        int ty = tq >> 1, tx = tq & 1;
        int kh = 2 * ty + 1 - ph;
        int kw = 2 * tx + 1 - pw;
        A2[i] = f2bf(w_dc[((ci * 256 + co) * 4 + kh) * 4 + kw]);
    } else if (blk < 6400) {
        int i = (blk - 4096) * 256 + t;
        A1[i] = f2bf(w_def[i]);
    } else if (blk < 6688) {
        int i = (blk - 6400) * 256 + t;
        int slot = i & 31;
        int oc = (i >> 5) & 31;
        int rest = i >> 10;
        int tap = rest % 9;
        int cc8 = rest / 9;
        int cgrp = (slot >> 3) ^ ((oc >> 1) & 3);
        int c = cc8 * 32 + (cgrp << 3) + (slot & 7);
        unsigned short v = 0;
        if (oc < 18) v = f2bf(w_off[(size_t)oc * 2304 + c * 9 + tap]);
        A2off[i] = v;
    } else {
        int blk2 = blk - 6688;
        int hw0 = (blk2 & 31) * 32;
        int c0 = ((blk2 >> 5) & 7) * 32;
        int b = blk2 >> 8;
        {
            int c_l = t >> 3, w4 = (t & 7) * 4;
            float4 v = *(const float4*)&x[(size_t)((b * 256 + c0 + c_l) * 1024) + hw0 + w4];
            tl[c_l][w4 + 0] = f2bf(v.x);
            tl[c_l][w4 + 1] = f2bf(v.y);
            tl[c_l][w4 + 2] = f2bf(v.z);
            tl[c_l][w4 + 3] = f2bf(v.w);
        }
        __syncthreads();
        {
            int hw_l = t >> 3, c4 = (t & 7) * 4;
            unsigned int s0 = tl[c4 + 0][hw_l];
            unsigned int s1 = tl[c4 + 1][hw_l];
            unsigned int s2 = tl[c4 + 2][hw_l];
            unsigned int s3 = tl[c4 + 3][hw_l];
            uint2 pk;
            pk.x = s0 | (s1 << 16);
            pk.y = s2 | (s3 << 16);
            *(uint2*)&xT[(size_t)((b * 1024 + hw0 + hw_l) * 256) + c0 + c4] = pk;
        }
    }
}

// ---------------- offset conv as MFMA GEMM ----------------
__global__ __launch_bounds__(256) void k_off_gemm(const unsigned short* __restrict__ A2off,
                                                  const unsigned short* __restrict__ xT,
                                                  const float* __restrict__ b_off,
                                                  float* __restrict__ off) {
    int hp = blockIdx.x, b = blockIdx.y;
    int h0 = hp * 2;
    int t = threadIdx.x;
    int lane = t & 63, wid = t >> 6;
    int l15 = lane & 15, g = lane >> 4;
    int swg = (l15 >> 1) & 3;
    __shared__ __align__(16) unsigned short As[9 * 32 * 32];
    __shared__ __align__(16) unsigned short Bsx[4 * 34 * 32];
    float4v acc[2];
    float4v z = {0.f, 0.f, 0.f, 0.f};
    acc[0] = z; acc[1] = z;

    int pos = wid * 16 + l15;
    int py = pos >> 5, px = pos & 31;

    for (int cc8 = 0; cc8 < 8; ++cc8) {
        __syncthreads();
        for (int idx = t; idx < 1152; idx += 256)
            stage1k(A2off + (size_t)cc8 * 9216 + idx * 8, (char*)As + idx * 16);
        for (int idx = t; idx < 544; idx += 256) {
            int r = idx / 136;
            int rem = idx - r * 136;
            int col = rem >> 2;
            int sgrp = rem & 3;
            int grp = sgrp ^ ((col >> 1) & 3);
            int h = h0 - 1 + r;
            int w = col - 1;
            uint4 v = {0u, 0u, 0u, 0u};
            if (h >= 0 && h < 32 && w >= 0 && w < 32)
                v = *(const uint4*)&xT[(size_t)((b * 1024 + h * 32 + w) * 256) + cc8 * 32 + grp * 8];
            *(uint4*)((char*)Bsx + ((r * 34 + col) << 6) + (sgrp << 4)) = v;
        }
        __syncthreads();
#pragma unroll
        for (int tap = 0; tap < 9; ++tap) {
            int ky = tap / 3, kx = tap - ky * 3;
            int col = px + kx;
            int rowr = py + ky;
            short8v bbf = *(const short8v*)((const char*)Bsx + ((rowr * 34 + col) << 6) +
                                            ((g ^ ((col >> 1) & 3)) << 4));
            short8v a0 = *(const short8v*)((const char*)As + tap * 2048 + l15 * 64 + ((g ^ swg) << 4));
            short8v a1 = *(const short8v*)((const char*)As + tap * 2048 + (16 + l15) * 64 + ((g ^ swg) << 4));
            acc[0] = __builtin_amdgcn_mfma_f32_16x16x32_bf16(a0, bbf, acc[0], 0, 0, 0);
            acc[1] = __builtin_amdgcn_mfma_f32_16x16x32_bf16(a1, bbf, acc[1], 0, 0, 0);
        }
    }
    int h = h0 + py;
#pragma unroll
    for (int r = 0; r < 4; ++r) {
        int oc = g * 4 + r;
        off[((size_t)(b * 18 + oc) << 10) + (h << 5) + px] = acc[0][r] + b_off[oc];
    }
    if (g == 0) {
#pragma unroll
        for (int r = 0; r < 2; ++r) {
            int oc = 16 + r;
            off[((size_t)(b * 18 + oc) << 10) + (h << 5) + px] = acc[1][r] + b_off[oc];
        }
    }
}

// ---------------- bilinear sampler: merged halves, block = (cg8, b) ----------------
__global__ __launch_bounds__(576) void k_sample(const float* __restrict__ x,
                                                const float* __restrict__ off,
                                                unsigned short* __restrict__ S) {
    int cg = blockIdx.x, b = blockIdx.y;
    int cbase = cg * 8;
    int t = threadIdx.x;
    int k = t >> 6, lane = t & 63;
    __shared__ __align__(16) unsigned int xpl[4 * 1156];
    __shared__ __align__(16) unsigned short sS[72 * 66];

    for (int u = t; u < 1024; u += 576) {
        int p = u >> 8, row = (u >> 3) & 31, cq = (u & 7) << 2;
        const float* src0 = x + ((size_t)(b * 256 + cbase + 2 * p) << 10) + (row << 5) + cq;
        float4 a = *(const float4*)src0;
        float4 c = *(const float4*)(src0 + 1024);
        uint4 pk;
        pk.x = (unsigned int)f2bf(a.x) | ((unsigned int)f2bf(c.x) << 16);
        pk.y = (unsigned int)f2bf(a.y) | ((unsigned int)f2bf(c.y) << 16);
        pk.z = (unsigned int)f2bf(a.z) | ((unsigned int)f2bf(c.z) << 16);
        pk.w = (unsigned int)f2bf(a.w) | ((unsigned int)f2bf(c.w) << 16);
        *(uint4*)&xpl[p * 1156 + row * 36 + cq] = pk;
    }

    int wr_row = t / 9, wr_q = t - wr_row * 9;
    const float* offk0 = off + ((size_t)(b * 18 + 2 * k) << 10);
    const float* offk1 = off + ((size_t)(b * 18 + 2 * k + 1) << 10);
    int ky = k / 3 - 1, kx = k % 3 - 1;
    __syncthreads();

    for (int chunk = 0; chunk < 16; ++chunk) {
        int pos = chunk * 64 + lane;
        int h = pos >> 5, w = pos & 31;
        float dy = offk0[pos];
        float dx = offk1[pos];
        float py = (float)(h + ky) + dy;
        float px = (float)(w + kx) + dx;
        float fy = floorf(py), fx = floorf(px);
        int y0i = (int)fy, x0i = (int)fx;
        float wy = py - fy, wxf = px - fx;
        float vy0 = (y0i >= 0 && y0i < 32) ? 1.f : 0.f;
        float vy1 = (y0i >= -1 && y0i < 31) ? 1.f : 0.f;
        float vx0 = (x0i >= 0 && x0i < 32) ? 1.f : 0.f;
        float vx1 = (x0i >= -1 && x0i < 31) ? 1.f : 0.f;
        int y0c = min(max(y0i, 0), 31), y1c = min(max(y0i + 1, 0), 31);
        int x0c = min(max(x0i, 0), 31), x1c = min(max(x0i + 1, 0), 31);
        float w00 = (1.f - wy) * (1.f - wxf) * vy0 * vx0;
        float w01 = (1.f - wy) * wxf * vy0 * vx1;
        float w10 = wy * (1.f - wxf) * vy1 * vx0;
        float w11 = wy * wxf * vy1 * vx1;
        int a00 = y0c * 36 + x0c, a01 = y0c * 36 + x1c;
        int a10 = y1c * 36 + x0c, a11 = y1c * 36 + x1c;
#pragma unroll
        for (int p = 0; p < 4; ++p) {
            const unsigned int* pl = xpl + p * 1156;
            unsigned int c00 = pl[a00], c01 = pl[a01], c10 = pl[a10], c11 = pl[a11];
            float e00 = __uint_as_float(c00 << 16), o00 = __uint_as_float(c00 & 0xFFFF0000u);
            float e01 = __uint_as_float(c01 << 16), o01 = __uint_as_float(c01 & 0xFFFF0000u);
            float e10 = __uint_as_float(c10 << 16), o10 = __uint_as_float(c10 & 0xFFFF0000u);
            float e11 = __uint_as_float(c11 << 16), o11 = __uint_as_float(c11 & 0xFFFF0000u);
            float ve = w00 * e00 + w01 * e01 + w10 * e10 + w11 * e11;
            float vo = w00 * o00 + w01 * o01 + w10 * o10 + w11 * o11;
            sS[((2 * p) * 9 + k) * 66 + lane] = f2bf(ve);
            sS[((2 * p + 1) * 9 + k) * 66 + lane] = f2bf(vo);
        }
        __syncthreads();
        {
            int basekc = wr_q * 8;
            unsigned int s0 = sS[(basekc + 0) * 66 + wr_row];
            unsigned int s1 = sS[(basekc + 1) * 66 + wr_row];
            unsigned int s2 = sS[(basekc + 2) * 66 + wr_row];
            unsigned int s3 = sS[(basekc + 3) * 66 + wr_row];
            unsigned int s4 = sS[(basekc + 4) * 66 + wr_row];
            unsigned int s5 = sS[(basekc + 5) * 66 + wr_row];
            unsigned int s6 = sS[(basekc + 6) * 66 + wr_row];
            unsigned int s7 = sS[(basekc + 7) * 66 + wr_row];
            uint4 qv;
            qv.x = s0 | (s1 << 16);
            qv.y = s2 | (s3 << 16);
            qv.z = s4 | (s5 << 16);
            qv.w = s6 | (s7 << 16);
            *(uint4*)(S + (size_t)(b * 1024 + chunk * 64 + wr_row) * 2304 + cg * 72 + wr_q * 8) = qv;
        }
        __syncthreads();
    }
}

// ---------------- GEMM1: BM=128, BN=64, KSTEP=64, counted-vmcnt dbuf, fused BN1, bf16 y1 ----------------
// grid (256 nb, 2 mb), 256 threads
__global__ __launch_bounds__(256) void k_gemm1(const unsigned short* __restrict__ A1,
                                               const unsigned short* __restrict__ S,
                                               const float* __restrict__ b_def,
                                               unsigned short* __restrict__ y1b,
                                               float* __restrict__ pstats1) {
    int nb = blockIdx.x, mb = blockIdx.y;
    int t = threadIdx.x;
    int lane = t & 63, wid = t >> 6;
    int wm = wid >> 1, wn = wid & 1;
    int l15 = lane & 15, g = lane >> 4;
    __shared__ __align__(16) unsigned short As[2][8192];  // 128 x 64
    __shared__ __align__(16) unsigned short Bs[2][4096];  // 64 x 64
    int m0 = mb * 128, n0 = nb * 64;
    int b = n0 >> 10, pos0 = n0 & 1023;

    const unsigned short* srcA[4];
    int dA[4];
    const unsigned short* srcB[2];
    int dB[2];
#pragma unroll
    for (int it = 0; it < 4; ++it) {
        int idx = t + it * 256;
        int r = idx >> 3, s8 = idx & 7, c = s8 ^ (r & 7);
        srcA[it] = A1 + (size_t)(m0 + r) * 2304 + c * 8;
        dA[it] = idx * 8;
    }
#pragma unroll
    for (int it = 0; it < 2; ++it) {
        int idx = t + it * 256;
        int r = idx >> 3, s8 = idx & 7, c = s8 ^ (r & 7);
        srcB[it] = S + (size_t)(n0 + r) * 2304 + c * 8;
        dB[it] = idx * 8;
    }

    float4v acc[4][2];
    float4v z = {0.f, 0.f, 0.f, 0.f};
#pragma unroll
    for (int i = 0; i < 4; ++i) { acc[i][0] = z; acc[i][1] = z; }

#pragma unroll
    for (int it = 0; it < 4; ++it) stage1k(srcA[it], &As[0][dA[it]]);
#pragma unroll
    for (int it = 0; it < 2; ++it) stage1k(srcB[it], &Bs[0][dB[it]]);

#define G1_COMPUTE(CUR)                                                                     \
    {                                                                                       \
        __builtin_amdgcn_s_setprio(1);                                                      \
        _Pragma("unroll")                                                                   \
        for (int kk = 0; kk < 2; ++kk) {                                                    \
            short8v a[4], bb[2];                                                            \
            _Pragma("unroll")                                                               \
            for (int mi = 0; mi < 4; ++mi) {                                                \
                int row = wm * 64 + mi * 16 + l15;                                          \
                int slot = ((kk << 2) + g) ^ (row & 7);                                     \
                a[mi] = *(const short8v*)((const char*)&As[CUR][0] + row * 128 + slot * 16);\
            }                                                                               \
            _Pragma("unroll")                                                               \
            for (int ni = 0; ni < 2; ++ni) {                                                \
                int row = wn * 32 + ni * 16 + l15;                                          \
                int slot = ((kk << 2) + g) ^ (row & 7);                                     \
                bb[ni] = *(const short8v*)((const char*)&Bs[CUR][0] + row * 128 + slot * 16);\
            }                                                                               \
            _Pragma("unroll")                                                               \
            for (int mi = 0; mi < 4; ++mi)                                                  \
                _Pragma("unroll")                                                           \
                for (int ni = 0; ni < 2; ++ni)                                              \
                    acc[mi][ni] = __builtin_amdgcn_mfma_f32_16x16x32_bf16(a[mi], bb[ni],    \
                                                                          acc[mi][ni], 0, 0, 0);\
        }                                                                                   \
        __builtin_amdgcn_s_setprio(0);                                                      \
    }

    for (int step = 0; step < 35; ++step) {
        int cur = step & 1;
        int koff = (step + 1) * 64;
#pragma unroll
        for (int it = 0; it < 4; ++it) stage1k(srcA[it] + koff, &As[cur ^ 1][dA[it]]);
#pragma unroll
        for (int it = 0; it < 2; ++it) stage1k(srcB[it] + koff, &Bs[cur ^ 1][dB[it]]);
        asm volatile("s_waitcnt vmcnt(6)" ::: "memory");
        __builtin_amdgcn_s_barrier();
        asm volatile("" ::: "memory");
        if (cur == 0) { G1_COMPUTE(0); } else { G1_COMPUTE(1); }
        asm volatile("" ::: "memory");
        __builtin_amdgcn_s_barrier();
    }
    asm volatile("s_waitcnt vmcnt(0)" ::: "memory");
    __builtin_amdgcn_s_barrier();
    asm volatile("" ::: "memory");
    G1_COMPUTE(1)  // step 35: cur = 1
#undef G1_COMPUTE

    // epilogue: bias + bf16 write + BN1 partial stats
    float* sred  = (float*)&As[0][0];  // [128][2]
    float* s2red = sred + 256;
#pragma unroll
    for (int mi = 0; mi < 4; ++mi) {
#pragma unroll
        for (int r = 0; r < 4; ++r) {
            int co = m0 + wm * 64 + mi * 16 + g * 4 + r;
            float bv = b_def[co];
            unsigned short* dst = y1b + ((size_t)(b * 256 + co) << 10) + pos0;
            float s = 0.f, s2 = 0.f;
#pragma unroll
            for (int ni = 0; ni < 2; ++ni) {
                float v = acc[mi][ni][r] + bv;
                dst[wn * 32 + ni * 16 + l15] = f2bf(v);
                s += v;
                s2 += v * v;
            }
#pragma unroll
            for (int m = 8; m >= 1; m >>= 1) {
                s  += __shfl_xor(s, m, 64);
                s2 += __shfl_xor(s2, m, 64);
            }
            if (l15 == 0) {
                int col = wm * 64 + mi * 16 + g * 4 + r;
                sred[col * 2 + wn]  = s;
                s2red[col * 2 + wn] = s2;
            }
        }
    }
    __syncthreads();
    if (t < 128) {
        float s  = sred[t * 2] + sred[t * 2 + 1];
        float s2 = s2red[t * 2] + s2red[t * 2 + 1];
        int ch = m0 + t;
        pstats1[ch * 256 + nb] = s;
        pstats1[65536 + ch * 256 + nb] = s2;
    }
}

// ---------------- GEMM2: convT by parity, KSTEP=32, counted-vmcnt dbuf, bf16 outP, fused BN2 ----------------
// LDS 32KB -> 4 blocks/CU. grid (128 nb, 2 mb, 4 p), 256 threads
__global__ __launch_bounds__(256) void k_gemm2(const unsigned short* __restrict__ A2,
                                               const unsigned short* __restrict__ y1T,
                                               unsigned short* __restrict__ outP,
                                               float* __restrict__ pstats2) {
    int nb = blockIdx.x, mb = blockIdx.y, p = blockIdx.z;
    int ph = p >> 1, pw = p & 1;
    int t = threadIdx.x;
    int lane = t & 63, wid = t >> 6;
    int wm = wid >> 1, wn = wid & 1;
    int l15 = lane & 15, g = lane >> 4;
    __shared__ __align__(16) unsigned short As[2][4096];  // 128 x 32
    __shared__ __align__(16) unsigned short Bs[2][4096];  // 128 x 32
    int m0 = mb * 128, n0 = nb * 128;
    int b = n0 >> 10, pos0 = n0 & 1023, oh0 = pos0 >> 5;

    int dtab[4];
#pragma unroll
    for (int tap = 0; tap < 4; ++tap) {
        int ty = tap >> 1, tx = tap & 1;
        int dy = ph ? (1 - ty) : (-ty);
        int dx = pw ? (1 - tx) : (-tx);
        dtab[tap] = (dy * 34 + dx) * 256;
    }
    const unsigned short* srcA[2];
    const unsigned short* srcB[2];
    int dstoff[2];
#pragma unroll
    for (int it = 0; it < 2; ++it) {
        int idx = t + it * 256;
        int r = idx >> 2, s4 = idx & 3, c = s4 ^ ((r >> 1) & 3);
        srcA[it] = A2 + (size_t)(p * 256 + m0 + r) * 1024 + c * 8;
        int ih = oh0 + (r >> 5) + 1;
        int iw = (r & 31) + 1;
        srcB[it] = y1T + ((size_t)(b * 34 + ih) * 34 + iw) * 256 + c * 8;
        dstoff[it] = idx * 8;
    }

    float4v acc[4][4];
    float4v z = {0.f, 0.f, 0.f, 0.f};
#pragma unroll
    for (int i = 0; i < 4; ++i)
#pragma unroll
        for (int j = 0; j < 4; ++j) acc[i][j] = z;

#pragma unroll
    for (int it = 0; it < 2; ++it) {
        stage1k(srcA[it], &As[0][dstoff[it]]);
        stage1k(srcB[it] + dtab[0], &Bs[0][dstoff[it]]);
    }

#define G2_COMPUTE(CUR)                                                                     \
    {                                                                                       \
        __builtin_amdgcn_s_setprio(1);                                                      \
        short8v a[4], bb[4];                                                                \
        _Pragma("unroll")                                                                   \
        for (int mi = 0; mi < 4; ++mi) {                                                    \
            int row = wm * 64 + mi * 16 + l15;                                              \
            int slot = g ^ ((row >> 1) & 3);                                                \
            a[mi] = *(const short8v*)((const char*)&As[CUR][0] + row * 64 + slot * 16);     \
        }                                                                                   \
        _Pragma("unroll")                                                                   \
        for (int ni = 0; ni < 4; ++ni) {                                                    \
            int row = wn * 64 + ni * 16 + l15;                                              \
            int slot = g ^ ((row >> 1) & 3);                                                \
            bb[ni] = *(const short8v*)((const char*)&Bs[CUR][0] + row * 64 + slot * 16);    \
        }                                                                                   \
        _Pragma("unroll")                                                                   \
        for (int mi = 0; mi < 4; ++mi)                                                      \
            _Pragma("unroll")                                                               \
            for (int ni = 0; ni < 4; ++ni)                                                  \
                acc[mi][ni] = __builtin_amdgcn_mfma_f32_16x16x32_bf16(a[mi], bb[ni],        \
                                                                      acc[mi][ni], 0, 0, 0);\
        __builtin_amdgcn_s_setprio(0);                                                      \
    }

#pragma unroll
    for (int step = 0; step < 31; ++step) {
        int cur = step & 1;
        int ns = step + 1;
        int tap = ns >> 3;
        int koff = ns * 32;
        int boff = dtab[tap] + (ns & 7) * 32;
#pragma unroll
        for (int it = 0; it < 2; ++it) {
            stage1k(srcA[it] + koff, &As[cur ^ 1][dstoff[it]]);
            stage1k(srcB[it] + boff, &Bs[cur ^ 1][dstoff[it]]);
        }
        asm volatile("s_waitcnt vmcnt(4)" ::: "memory");
        __builtin_amdgcn_s_barrier();
        asm volatile("" ::: "memory");
        if (cur == 0) { G2_COMPUTE(0); } else { G2_COMPUTE(1); }
        asm volatile("" ::: "memory");
        __builtin_amdgcn_s_barrier();
    }
    asm volatile("s_waitcnt vmcnt(0)" ::: "memory");
    __builtin_amdgcn_s_barrier();
    asm volatile("" ::: "memory");
    G2_COMPUTE(1)  // step 31: cur = 1
#undef G2_COMPUTE

    // coalesced bf16 write to parity-planar outP
#pragma unroll
    for (int mi = 0; mi < 4; ++mi) {
#pragma unroll
        for (int r = 0; r < 4; ++r) {
            int co = m0 + wm * 64 + mi * 16 + g * 4 + r;
            unsigned short* dst = outP + ((size_t)((p * 16 + b) * 256 + co) << 10) + pos0;
#pragma unroll
            for (int ni = 0; ni < 4; ++ni)
                dst[wn * 64 + ni * 16 + l15] = f2bf(acc[mi][ni][r]);
        }
    }
    // fused BN2 partial stats (from fp32 accs)
    float* sred  = (float*)&As[0][0];
    float* s2red = sred + 256;
#pragma unroll
    for (int mi = 0; mi < 4; ++mi) {
#pragma unroll
        for (int r = 0; r < 4; ++r) {
            float s = 0.f, s2 = 0.f;
#pragma unroll
            for (int ni = 0; ni < 4; ++ni) {
                float v = acc[mi][ni][r];
                s += v;
                s2 += v * v;
            }
#pragma unroll
            for (int m = 8; m >= 1; m >>= 1) {
                s  += __shfl_xor(s, m, 64);
                s2 += __shfl_xor(s2, m, 64);
            }
            if (l15 == 0) {
                int col = wm * 64 + mi * 16 + g * 4 + r;
                sred[col * 2 + wn]  = s;
                s2red[col * 2 + wn] = s2;
            }
        }
    }
    __syncthreads();
    if (t < 128) {
        float s  = sred[t * 2] + sred[t * 2 + 1];
        float s2 = s2red[t * 2] + s2red[t * 2 + 1];
        int row = p * 128 + nb;
        int ch = m0 + t;
        pstats2[ch * 512 + row] = s;
        pstats2[131072 + ch * 512 + row] = s2;
    }
}

// ---------------- parallel BN finisher ----------------
__global__ __launch_bounds__(256) void k_bnfin_par(const float* __restrict__ pstats, int nparts,
                                                   float n,
                                                   float* __restrict__ mean, float* __restrict__ rstd) {
    int ch = blockIdx.x;
    int t = threadIdx.x;
    float s = 0.f, s2 = 0.f;
    for (int j = t; j < nparts; j += 256) {
        s  += pstats[ch * nparts + j];
        s2 += pstats[256 * nparts + ch * nparts + j];
    }
    __shared__ float rs[256], rs2[256];
    rs[t] = s; rs2[t] = s2;
    __syncthreads();
    for (int d = 128; d > 0; d >>= 1) {
        if (t < d) { rs[t] += rs[t + d]; rs2[t] += rs2[t + d]; }
        __syncthreads();
    }
    if (t == 0) {
        float m = rs[0] / n;
        float var = rs2[0] / n - m * m;
        mean[ch] = m;
        rstd[ch] = rsqrtf(var + 1e-5f);
    }
}

// ---------------- BN+SiLU on bf16 y1 -> channel-last padded bf16 y1T, halo zeroed ----------------
__global__ __launch_bounds__(256) void k_bnsilu_padT(const unsigned short* __restrict__ y1b,
                                                     const float* __restrict__ mean,
                                                     const float* __restrict__ rstd,
                                                     const float* __restrict__ gamma,
                                                     const float* __restrict__ beta,
                                                     unsigned short* __restrict__ y1T) {
    int py = blockIdx.x, cg = blockIdx.y, b = blockIdx.z;
    int c0 = cg * 32;
    int t = threadIdx.x;
    uint2 zz; zz.x = 0u; zz.y = 0u;
    if (py == 0 || py == 33) {
        for (int u = t; u < 272; u += 256) {
            int col = u >> 3, c4 = (u & 7) * 4;
            *(uint2*)&y1T[((size_t)(b * 34 + py) * 34 + col) * 256 + c0 + c4] = zz;
        }
        return;
    }
    __shared__ unsigned short tl[32][36];
    int iy = py - 1;
    {
        int c_l = t >> 3, px4 = (t & 7) * 4;
        int ch = c0 + c_l;
        float m = mean[ch], rs = rstd[ch], ga = gamma[ch], be = beta[ch];
        uint2 v = *(const uint2*)&y1b[(size_t)((b * 256 + ch) << 10) + (iy << 5) + px4];
        float f0 = __uint_as_float(v.x << 16), f1 = __uint_as_float(v.x & 0xFFFF0000u);
        float f2 = __uint_as_float(v.y << 16), f3 = __uint_as_float(v.y & 0xFFFF0000u);
        tl[c_l][px4 + 0] = f2bf(silu(ga * (f0 - m) * rs + be));
        tl[c_l][px4 + 1] = f2bf(silu(ga * (f1 - m) * rs + be));
        tl[c_l][px4 + 2] = f2bf(silu(ga * (f2 - m) * rs + be));
        tl[c_l][px4 + 3] = f2bf(silu(ga * (f3 - m) * rs + be));
    }
    __syncthreads();
    {
        int px = t >> 3, c4 = (t & 7) * 4;
        unsigned int s0 = tl[c4 + 0][px];
        unsigned int s1 = tl[c4 + 1][px];
        unsigned int s2 = tl[c4 + 2][px];
        unsigned int s3 = tl[c4 + 3][px];
        uint2 pk;
        pk.x = s0 | (s1 << 16);
        pk.y = s2 | (s3 << 16);
        *(uint2*)&y1T[((size_t)(b * 34 + py) * 34 + (px + 1)) * 256 + c0 + c4] = pk;
    }
    if (t < 16) {
        int col = (t >> 3) ? 33 : 0;
        int c4 = (t & 7) * 4;
        *(uint2*)&y1T[((size_t)(b * 34 + py) * 34 + col) * 256 + c0 + c4] = zz;
    }
}

// ---------------- final: BN+SiLU + parity interleave (bf16 outP) -> out ----------------
__global__ __launch_bounds__(256) void k_bnsilu_out(const unsigned short* __restrict__ outP,
                                                    const float* __restrict__ mean,
                                                    const float* __restrict__ rstd,
                                                    const float* __restrict__ gamma,
                                                    const float* __restrict__ beta,
                                                    float* __restrict__ out) {
    unsigned int i = blockIdx.x * 256 + threadIdx.x;
    int ow4 = i & 15;
    int oh = (i >> 4) & 63;
    int co = (i >> 10) & 255;
    int b  = i >> 18;
    int p0 = (oh & 1) * 2;
    int pos = ((oh >> 1) << 5) + ow4 * 2;
    const unsigned short* pl0 = outP + ((size_t)((p0 * 16 + b) * 256 + co) << 10) + pos;
    const unsigned short* pl1 = pl0 + ((size_t)16 * 256 << 10);
    unsigned int ue = *(const unsigned int*)pl0;
    unsigned int uo = *(const unsigned int*)pl1;
    float ex = __uint_as_float(ue << 16), ey = __uint_as_float(ue & 0xFFFF0000u);
    float ox = __uint_as_float(uo << 16), oy = __uint_as_float(uo & 0xFFFF0000u);
    float m = mean[co], rs = rstd[co], ga = gamma[co], be = beta[co];
    float4 v;
    v.x = silu(ga * (ex - m) * rs + be);
    v.y = silu(ga * (ox - m) * rs + be);
    v.z = silu(ga * (ey - m) * rs + be);
    v.w = silu(ga * (oy - m) * rs + be);
    *(float4*)&out[((size_t)(b * 256 + co) << 12) + (oh << 6) + ow4 * 4] = v;
}

extern "C" void kernel_launch(void* const* d_in, const int* in_sizes, int n_in,
                              void* d_out, int out_size, void* d_ws, size_t ws_size,
                              hipStream_t stream) {
    const float* x      = (const float*)d_in[0];
    const float* w_off  = (const float*)d_in[1];
    const float* b_off  = (const float*)d_in[2];
    const float* w_def  = (const float*)d_in[3];
    const float* b_def  = (const float*)d_in[4];
    const float* gamma1 = (const float*)d_in[5];
    const float* beta1  = (const float*)d_in[6];
    const float* w_dc   = (const float*)d_in[7];
    const float* gamma2 = (const float*)d_in[8];
    const float* beta2  = (const float*)d_in[9];
    float* out = (float*)d_out;

    char* base = (char*)d_ws;
    unsigned short* S    = (unsigned short*)base;                 // 75,497,472 B (dead after gemm1)
    unsigned short* y1b  = (unsigned short*)(base + 75497472);    //  8,388,608 B (bf16)
    unsigned short* y1T  = (unsigned short*)(base + 92274688);    //  9,469,952 B (padded ch-last)
    unsigned short* A1   = (unsigned short*)(base + 101744640);   //  1,179,648 B
    unsigned short* A2   = (unsigned short*)(base + 102924288);   //  2,097,152 B
    float*          off  = (float*)(base + 105021440);            //  1,179,648 B
    float*          stats = (float*)(base + 106201088);           //  1,024 B
    float* mean1 = stats, *rstd1 = stats + 256, *mean2 = stats + 512, *rstd2 = stats + 768;
    float* pstats1 = off;
    float* pstats2 = off;
    unsigned short* xT    = (unsigned short*)base;                //  8,388,608 B (dead after off_gemm)
    unsigned short* A2off = (unsigned short*)(base + 8388608);    //    147,456 B
    unsigned short* outP = (unsigned short*)base;  // 33,554,432 B, aliases S after gemm1

    k_prep_all<<<10784, 256, 0, stream>>>(w_def, w_dc, w_off, x, A1, A2, A2off, xT);
    k_off_gemm<<<dim3(16, 16), 256, 0, stream>>>(A2off, xT, b_off, off);
    k_sample<<<dim3(32, 16), 576, 0, stream>>>(x, off, S);
    k_gemm1<<<dim3(256, 2), 256, 0, stream>>>(A1, S, b_def, y1b, pstats1);
    k_bnfin_par<<<256, 256, 0, stream>>>(pstats1, 256, 16384.f, mean1, rstd1);
    k_bnsilu_padT<<<dim3(34, 8, 16), 256, 0, stream>>>(y1b, mean1, rstd1, gamma1, beta1, y1T);
    k_gemm2<<<dim3(128, 2, 4), 256, 0, stream>>>(A2, y1T, outP, pstats2);
    k_bnfin_par<<<256, 256, 0, stream>>>(pstats2, 512, 65536.f, mean2, rstd2);
    k_bnsilu_out<<<16384, 256, 0, stream>>>(outP, mean2, rstd2, gamma2, beta2, out);
}

// Round 16
// 174.060 us; speedup vs baseline: 1.1424x; 1.0492x over previous
//
#include <hip/hip_runtime.h>
#include <math.h>

#ifdef __has_builtin
#if __has_builtin(__builtin_amdgcn_global_load_lds)
#define HAS_GLL 1
#endif
#endif
#ifndef HAS_GLL
#define HAS_GLL 0
#endif

typedef __attribute__((ext_vector_type(8))) short short8v;
typedef __attribute__((ext_vector_type(4))) float float4v;

__device__ __forceinline__ unsigned short f2bf(float f) {
    unsigned int u = __float_as_uint(f);
    u += 0x7fffu + ((u >> 16) & 1u);
    return (unsigned short)(u >> 16);
}

__device__ __forceinline__ float silu(float y) { return y / (1.f + expf(-y)); }

// wave stages 1KB into LDS: lane i -> ldsbase + 16*i, from per-lane gsrc (16B each)
__device__ __forceinline__ void stage1k(const void* gsrc, void* ldsbase) {
#if HAS_GLL
    __builtin_amdgcn_global_load_lds((const __attribute__((address_space(1))) unsigned int*)gsrc,
                                     (__attribute__((address_space(3))) unsigned int*)ldsbase,
                                     16, 0, 0);
#else
    int lane = threadIdx.x & 63;
    *(float4*)((char*)ldsbase + lane * 16) = *(const float4*)gsrc;
#endif
}

// ---------------- merged prep: A2 | A1 | A2off | xT ----------------
__global__ __launch_bounds__(256) void k_prep_all(const float* __restrict__ w_def,
                                                  const float* __restrict__ w_dc,
                                                  const float* __restrict__ w_off,
                                                  const float* __restrict__ x,
                                                  unsigned short* __restrict__ A1,
                                                  unsigned short* __restrict__ A2,
                                                  unsigned short* __restrict__ A2off,
                                                  unsigned short* __restrict__ xT) {
    int blk = blockIdx.x;
    int t = threadIdx.x;
    __shared__ unsigned short tl[32][36];
    if (blk < 4096) {
        int i = blk * 256 + t;
        int ci = i & 255;
        int tq = (i >> 8) & 3;
        int co = (i >> 10) & 255;
        int p  = i >> 18;
        int ph = p >> 1, pw = p & 1;
        int ty = tq >> 1, tx = tq & 1;
        int kh = 2 * ty + 1 - ph;
        int kw = 2 * tx + 1 - pw;
        A2[i] = f2bf(w_dc[((ci * 256 + co) * 4 + kh) * 4 + kw]);
    } else if (blk < 6400) {
        int i = (blk - 4096) * 256 + t;
        A1[i] = f2bf(w_def[i]);
    } else if (blk < 6688) {
        int i = (blk - 6400) * 256 + t;
        int slot = i & 31;
        int oc = (i >> 5) & 31;
        int rest = i >> 10;
        int tap = rest % 9;
        int cc8 = rest / 9;
        int cgrp = (slot >> 3) ^ ((oc >> 1) & 3);
        int c = cc8 * 32 + (cgrp << 3) + (slot & 7);
        unsigned short v = 0;
        if (oc < 18) v = f2bf(w_off[(size_t)oc * 2304 + c * 9 + tap]);
        A2off[i] = v;
    } else {
        int blk2 = blk - 6688;
        int hw0 = (blk2 & 31) * 32;
        int c0 = ((blk2 >> 5) & 7) * 32;
        int b = blk2 >> 8;
        {
            int c_l = t >> 3, w4 = (t & 7) * 4;
            float4 v = *(const float4*)&x[(size_t)((b * 256 + c0 + c_l) * 1024) + hw0 + w4];
            tl[c_l][w4 + 0] = f2bf(v.x);
            tl[c_l][w4 + 1] = f2bf(v.y);
            tl[c_l][w4 + 2] = f2bf(v.z);
            tl[c_l][w4 + 3] = f2bf(v.w);
        }
        __syncthreads();
        {
            int hw_l = t >> 3, c4 = (t & 7) * 4;
            unsigned int s0 = tl[c4 + 0][hw_l];
            unsigned int s1 = tl[c4 + 1][hw_l];
            unsigned int s2 = tl[c4 + 2][hw_l];
            unsigned int s3 = tl[c4 + 3][hw_l];
            uint2 pk;
            pk.x = s0 | (s1 << 16);
            pk.y = s2 | (s3 << 16);
            *(uint2*)&xT[(size_t)((b * 1024 + hw0 + hw_l) * 256) + c0 + c4] = pk;
        }
    }
}

// ---------------- offset conv as MFMA GEMM ----------------
__global__ __launch_bounds__(256) void k_off_gemm(const unsigned short* __restrict__ A2off,
                                                  const unsigned short* __restrict__ xT,
                                                  const float* __restrict__ b_off,
                                                  float* __restrict__ off) {
    int hp = blockIdx.x, b = blockIdx.y;
    int h0 = hp * 2;
    int t = threadIdx.x;
    int lane = t & 63, wid = t >> 6;
    int l15 = lane & 15, g = lane >> 4;
    int swg = (l15 >> 1) & 3;
    __shared__ __align__(16) unsigned short As[9 * 32 * 32];
    __shared__ __align__(16) unsigned short Bsx[4 * 34 * 32];
    float4v acc[2];
    float4v z = {0.f, 0.f, 0.f, 0.f};
    acc[0] = z; acc[1] = z;

    int pos = wid * 16 + l15;
    int py = pos >> 5, px = pos & 31;

    for (int cc8 = 0; cc8 < 8; ++cc8) {
        __syncthreads();
        for (int idx = t; idx < 1152; idx += 256)
            stage1k(A2off + (size_t)cc8 * 9216 + idx * 8, (char*)As + idx * 16);
        for (int idx = t; idx < 544; idx += 256) {
            int r = idx / 136;
            int rem = idx - r * 136;
            int col = rem >> 2;
            int sgrp = rem & 3;
            int grp = sgrp ^ ((col >> 1) & 3);
            int h = h0 - 1 + r;
            int w = col - 1;
            uint4 v = {0u, 0u, 0u, 0u};
            if (h >= 0 && h < 32 && w >= 0 && w < 32)
                v = *(const uint4*)&xT[(size_t)((b * 1024 + h * 32 + w) * 256) + cc8 * 32 + grp * 8];
            *(uint4*)((char*)Bsx + ((r * 34 + col) << 6) + (sgrp << 4)) = v;
        }
        __syncthreads();
#pragma unroll
        for (int tap = 0; tap < 9; ++tap) {
            int ky = tap / 3, kx = tap - ky * 3;
            int col = px + kx;
            int rowr = py + ky;
            short8v bbf = *(const short8v*)((const char*)Bsx + ((rowr * 34 + col) << 6) +
                                            ((g ^ ((col >> 1) & 3)) << 4));
            short8v a0 = *(const short8v*)((const char*)As + tap * 2048 + l15 * 64 + ((g ^ swg) << 4));
            short8v a1 = *(const short8v*)((const char*)As + tap * 2048 + (16 + l15) * 64 + ((g ^ swg) << 4));
            acc[0] = __builtin_amdgcn_mfma_f32_16x16x32_bf16(a0, bbf, acc[0], 0, 0, 0);
            acc[1] = __builtin_amdgcn_mfma_f32_16x16x32_bf16(a1, bbf, acc[1], 0, 0, 0);
        }
    }
    int h = h0 + py;
#pragma unroll
    for (int r = 0; r < 4; ++r) {
        int oc = g * 4 + r;
        off[((size_t)(b * 18 + oc) << 10) + (h << 5) + px] = acc[0][r] + b_off[oc];
    }
    if (g == 0) {
#pragma unroll
        for (int r = 0; r < 2; ++r) {
            int oc = 16 + r;
            off[((size_t)(b * 18 + oc) << 10) + (h << 5) + px] = acc[1][r] + b_off[oc];
        }
    }
}

// ---------------- bilinear sampler: merged halves, block = (cg8, b) ----------------
__global__ __launch_bounds__(576) void k_sample(const float* __restrict__ x,
                                                const float* __restrict__ off,
                                                unsigned short* __restrict__ S) {
    int cg = blockIdx.x, b = blockIdx.y;
    int cbase = cg * 8;
    int t = threadIdx.x;
    int k = t >> 6, lane = t & 63;
    __shared__ __align__(16) unsigned int xpl[4 * 1156];
    __shared__ __align__(16) unsigned short sS[72 * 66];

    for (int u = t; u < 1024; u += 576) {
        int p = u >> 8, row = (u >> 3) & 31, cq = (u & 7) << 2;
        const float* src0 = x + ((size_t)(b * 256 + cbase + 2 * p) << 10) + (row << 5) + cq;
        float4 a = *(const float4*)src0;
        float4 c = *(const float4*)(src0 + 1024);
        uint4 pk;
        pk.x = (unsigned int)f2bf(a.x) | ((unsigned int)f2bf(c.x) << 16);
        pk.y = (unsigned int)f2bf(a.y) | ((unsigned int)f2bf(c.y) << 16);
        pk.z = (unsigned int)f2bf(a.z) | ((unsigned int)f2bf(c.z) << 16);
        pk.w = (unsigned int)f2bf(a.w) | ((unsigned int)f2bf(c.w) << 16);
        *(uint4*)&xpl[p * 1156 + row * 36 + cq] = pk;
    }

    int wr_row = t / 9, wr_q = t - wr_row * 9;
    const float* offk0 = off + ((size_t)(b * 18 + 2 * k) << 10);
    const float* offk1 = off + ((size_t)(b * 18 + 2 * k + 1) << 10);
    int ky = k / 3 - 1, kx = k % 3 - 1;
    __syncthreads();

    for (int chunk = 0; chunk < 16; ++chunk) {
        int pos = chunk * 64 + lane;
        int h = pos >> 5, w = pos & 31;
        float dy = offk0[pos];
        float dx = offk1[pos];
        float py = (float)(h + ky) + dy;
        float px = (float)(w + kx) + dx;
        float fy = floorf(py), fx = floorf(px);
        int y0i = (int)fy, x0i = (int)fx;
        float wy = py - fy, wxf = px - fx;
        float vy0 = (y0i >= 0 && y0i < 32) ? 1.f : 0.f;
        float vy1 = (y0i >= -1 && y0i < 31) ? 1.f : 0.f;
        float vx0 = (x0i >= 0 && x0i < 32) ? 1.f : 0.f;
        float vx1 = (x0i >= -1 && x0i < 31) ? 1.f : 0.f;
        int y0c = min(max(y0i, 0), 31), y1c = min(max(y0i + 1, 0), 31);
        int x0c = min(max(x0i, 0), 31), x1c = min(max(x0i + 1, 0), 31);
        float w00 = (1.f - wy) * (1.f - wxf) * vy0 * vx0;
        float w01 = (1.f - wy) * wxf * vy0 * vx1;
        float w10 = wy * (1.f - wxf) * vy1 * vx0;
        float w11 = wy * wxf * vy1 * vx1;
        int a00 = y0c * 36 + x0c, a01 = y0c * 36 + x1c;
        int a10 = y1c * 36 + x0c, a11 = y1c * 36 + x1c;
#pragma unroll
        for (int p = 0; p < 4; ++p) {
            const unsigned int* pl = xpl + p * 1156;
            unsigned int c00 = pl[a00], c01 = pl[a01], c10 = pl[a10], c11 = pl[a11];
            float e00 = __uint_as_float(c00 << 16), o00 = __uint_as_float(c00 & 0xFFFF0000u);
            float e01 = __uint_as_float(c01 << 16), o01 = __uint_as_float(c01 & 0xFFFF0000u);
            float e10 = __uint_as_float(c10 << 16), o10 = __uint_as_float(c10 & 0xFFFF0000u);
            float e11 = __uint_as_float(c11 << 16), o11 = __uint_as_float(c11 & 0xFFFF0000u);
            float ve = w00 * e00 + w01 * e01 + w10 * e10 + w11 * e11;
            float vo = w00 * o00 + w01 * o01 + w10 * o10 + w11 * o11;
            sS[((2 * p) * 9 + k) * 66 + lane] = f2bf(ve);
            sS[((2 * p + 1) * 9 + k) * 66 + lane] = f2bf(vo);
        }
        __syncthreads();
        {
            int basekc = wr_q * 8;
            unsigned int s0 = sS[(basekc + 0) * 66 + wr_row];
            unsigned int s1 = sS[(basekc + 1) * 66 + wr_row];
            unsigned int s2 = sS[(basekc + 2) * 66 + wr_row];
            unsigned int s3 = sS[(basekc + 3) * 66 + wr_row];
            unsigned int s4 = sS[(basekc + 4) * 66 + wr_row];
            unsigned int s5 = sS[(basekc + 5) * 66 + wr_row];
            unsigned int s6 = sS[(basekc + 6) * 66 + wr_row];
            unsigned int s7 = sS[(basekc + 7) * 66 + wr_row];
            uint4 qv;
            qv.x = s0 | (s1 << 16);
            qv.y = s2 | (s3 << 16);
            qv.z = s4 | (s5 << 16);
            qv.w = s6 | (s7 << 16);
            *(uint4*)(S + (size_t)(b * 1024 + chunk * 64 + wr_row) * 2304 + cg * 72 + wr_q * 8) = qv;
        }
        __syncthreads();
    }
}

// ---------------- GEMM1: BM=128, BN=64, KSTEP=64, counted-vmcnt dbuf, fused BN1, bf16 y1 ----------------
// grid (256 nb, 2 mb), 256 threads
__global__ __launch_bounds__(256) void k_gemm1(const unsigned short* __restrict__ A1,
                                               const unsigned short* __restrict__ S,
                                               const float* __restrict__ b_def,
                                               unsigned short* __restrict__ y1b,
                                               float* __restrict__ pstats1) {
    int nb = blockIdx.x, mb = blockIdx.y;
    int t = threadIdx.x;
    int lane = t & 63, wid = t >> 6;
    int wm = wid >> 1, wn = wid & 1;
    int l15 = lane & 15, g = lane >> 4;
    __shared__ __align__(16) unsigned short As[2][8192];  // 128 x 64
    __shared__ __align__(16) unsigned short Bs[2][4096];  // 64 x 64
    int m0 = mb * 128, n0 = nb * 64;
    int b = n0 >> 10, pos0 = n0 & 1023;

    const unsigned short* srcA[4];
    int dA[4];
    const unsigned short* srcB[2];
    int dB[2];
#pragma unroll
    for (int it = 0; it < 4; ++it) {
        int idx = t + it * 256;
        int r = idx >> 3, s8 = idx & 7, c = s8 ^ (r & 7);
        srcA[it] = A1 + (size_t)(m0 + r) * 2304 + c * 8;
        dA[it] = idx * 8;
    }
#pragma unroll
    for (int it = 0; it < 2; ++it) {
        int idx = t + it * 256;
        int r = idx >> 3, s8 = idx & 7, c = s8 ^ (r & 7);
        srcB[it] = S + (size_t)(n0 + r) * 2304 + c * 8;
        dB[it] = idx * 8;
    }

    float4v acc[4][2];
    float4v z = {0.f, 0.f, 0.f, 0.f};
#pragma unroll
    for (int i = 0; i < 4; ++i) { acc[i][0] = z; acc[i][1] = z; }

#pragma unroll
    for (int it = 0; it < 4; ++it) stage1k(srcA[it], &As[0][dA[it]]);
#pragma unroll
    for (int it = 0; it < 2; ++it) stage1k(srcB[it], &Bs[0][dB[it]]);

#define G1_COMPUTE(CUR)                                                                     \
    {                                                                                       \
        __builtin_amdgcn_s_setprio(1);                                                      \
        _Pragma("unroll")                                                                   \
        for (int kk = 0; kk < 2; ++kk) {                                                    \
            short8v a[4], bb[2];                                                            \
            _Pragma("unroll")                                                               \
            for (int mi = 0; mi < 4; ++mi) {                                                \
                int row = wm * 64 + mi * 16 + l15;                                          \
                int slot = ((kk << 2) + g) ^ (row & 7);                                     \
                a[mi] = *(const short8v*)((const char*)&As[CUR][0] + row * 128 + slot * 16);\
            }                                                                               \
            _Pragma("unroll")                                                               \
            for (int ni = 0; ni < 2; ++ni) {                                                \
                int row = wn * 32 + ni * 16 + l15;                                          \
                int slot = ((kk << 2) + g) ^ (row & 7);                                     \
                bb[ni] = *(const short8v*)((const char*)&Bs[CUR][0] + row * 128 + slot * 16);\
            }                                                                               \
            _Pragma("unroll")                                                               \
            for (int mi = 0; mi < 4; ++mi)                                                  \
                _Pragma("unroll")                                                           \
                for (int ni = 0; ni < 2; ++ni)                                              \
                    acc[mi][ni] = __builtin_amdgcn_mfma_f32_16x16x32_bf16(a[mi], bb[ni],    \
                                                                          acc[mi][ni], 0, 0, 0);\
        }                                                                                   \
        __builtin_amdgcn_s_setprio(0);                                                      \
    }

    for (int step = 0; step < 35; ++step) {
        int cur = step & 1;
        int koff = (step + 1) * 64;
#pragma unroll
        for (int it = 0; it < 4; ++it) stage1k(srcA[it] + koff, &As[cur ^ 1][dA[it]]);
#pragma unroll
        for (int it = 0; it < 2; ++it) stage1k(srcB[it] + koff, &Bs[cur ^ 1][dB[it]]);
        asm volatile("s_waitcnt vmcnt(6)" ::: "memory");
        __builtin_amdgcn_s_barrier();
        asm volatile("" ::: "memory");
        if (cur == 0) { G1_COMPUTE(0); } else { G1_COMPUTE(1); }
        asm volatile("" ::: "memory");
        __builtin_amdgcn_s_barrier();
    }
    asm volatile("s_waitcnt vmcnt(0)" ::: "memory");
    __builtin_amdgcn_s_barrier();
    asm volatile("" ::: "memory");
    G1_COMPUTE(1)  // step 35: cur = 1
#undef G1_COMPUTE

    // epilogue: bias + bf16 write + BN1 partial stats
    float* sred  = (float*)&As[0][0];  // [128][2]
    float* s2red = sred + 256;
#pragma unroll
    for (int mi = 0; mi < 4; ++mi) {
#pragma unroll
        for (int r = 0; r < 4; ++r) {
            int co = m0 + wm * 64 + mi * 16 + g * 4 + r;
            float bv = b_def[co];
            unsigned short* dst = y1b + ((size_t)(b * 256 + co) << 10) + pos0;
            float s = 0.f, s2 = 0.f;
#pragma unroll
            for (int ni = 0; ni < 2; ++ni) {
                float v = acc[mi][ni][r] + bv;
                dst[wn * 32 + ni * 16 + l15] = f2bf(v);
                s += v;
                s2 += v * v;
            }
#pragma unroll
            for (int m = 8; m >= 1; m >>= 1) {
                s  += __shfl_xor(s, m, 64);
                s2 += __shfl_xor(s2, m, 64);
            }
            if (l15 == 0) {
                int col = wm * 64 + mi * 16 + g * 4 + r;
                sred[col * 2 + wn]  = s;
                s2red[col * 2 + wn] = s2;
            }
        }
    }
    __syncthreads();
    if (t < 128) {
        float s  = sred[t * 2] + sred[t * 2 + 1];
        float s2 = s2red[t * 2] + s2red[t * 2 + 1];
        int ch = m0 + t;
        pstats1[ch * 256 + nb] = s;
        pstats1[65536 + ch * 256 + nb] = s2;
    }
}

// ---------------- GEMM2: convT by parity, KSTEP=64, counted-vmcnt dbuf, bf16 outP, fused BN2 ----------------
__global__ __launch_bounds__(256) void k_gemm2(const unsigned short* __restrict__ A2,
                                               const unsigned short* __restrict__ y1T,
                                               unsigned short* __restrict__ outP,
                                               float* __restrict__ pstats2) {
    int nb = blockIdx.x, mb = blockIdx.y, p = blockIdx.z;
    int ph = p >> 1, pw = p & 1;
    int t = threadIdx.x;
    int lane = t & 63, wid = t >> 6;
    int wm = wid >> 1, wn = wid & 1;
    int l15 = lane & 15, g = lane >> 4;
    __shared__ __align__(16) unsigned short As[2][8192];
    __shared__ __align__(16) unsigned short Bs[2][8192];
    int m0 = mb * 128, n0 = nb * 128;
    int b = n0 >> 10, pos0 = n0 & 1023, oh0 = pos0 >> 5;

    int dtab[4];
#pragma unroll
    for (int tap = 0; tap < 4; ++tap) {
        int ty = tap >> 1, tx = tap & 1;
        int dy = ph ? (1 - ty) : (-ty);
        int dx = pw ? (1 - tx) : (-tx);
        dtab[tap] = (dy * 34 + dx) * 256;
    }
    const unsigned short* srcA[4];
    const unsigned short* srcB[4];
    int dstoff[4];
#pragma unroll
    for (int it = 0; it < 4; ++it) {
        int idx = t + it * 256;
        int r = idx >> 3, s8 = idx & 7, c = s8 ^ (r & 7);
        srcA[it] = A2 + (size_t)(p * 256 + m0 + r) * 1024 + c * 8;
        int ih = oh0 + (r >> 5) + 1;
        int iw = (r & 31) + 1;
        srcB[it] = y1T + ((size_t)(b * 34 + ih) * 34 + iw) * 256 + c * 8;
        dstoff[it] = idx * 8;
    }

    float4v acc[4][4];
    float4v z = {0.f, 0.f, 0.f, 0.f};
#pragma unroll
    for (int i = 0; i < 4; ++i)
#pragma unroll
        for (int j = 0; j < 4; ++j) acc[i][j] = z;

#pragma unroll
    for (int it = 0; it < 4; ++it) {
        stage1k(srcA[it], &As[0][dstoff[it]]);
        stage1k(srcB[it] + dtab[0], &Bs[0][dstoff[it]]);
    }

#define G2_COMPUTE(CUR)                                                                     \
    {                                                                                       \
        __builtin_amdgcn_s_setprio(1);                                                      \
        _Pragma("unroll")                                                                   \
        for (int kk = 0; kk < 2; ++kk) {                                                    \
            short8v a[4], bb[4];                                                            \
            _Pragma("unroll")                                                               \
            for (int mi = 0; mi < 4; ++mi) {                                                \
                int row = wm * 64 + mi * 16 + l15;                                          \
                int slot = ((kk << 2) + g) ^ (row & 7);                                     \
                a[mi] = *(const short8v*)((const char*)&As[CUR][0] + row * 128 + slot * 16);\
            }                                                                               \
            _Pragma("unroll")                                                               \
            for (int ni = 0; ni < 4; ++ni) {                                                \
                int row = wn * 64 + ni * 16 + l15;                                          \
                int slot = ((kk << 2) + g) ^ (row & 7);                                     \
                bb[ni] = *(const short8v*)((const char*)&Bs[CUR][0] + row * 128 + slot * 16);\
            }                                                                               \
            _Pragma("unroll")                                                               \
            for (int mi = 0; mi < 4; ++mi)                                                  \
                _Pragma("unroll")                                                           \
                for (int ni = 0; ni < 4; ++ni)                                              \
                    acc[mi][ni] = __builtin_amdgcn_mfma_f32_16x16x32_bf16(a[mi], bb[ni],    \
                                                                          acc[mi][ni], 0, 0, 0);\
        }                                                                                   \
        __builtin_amdgcn_s_setprio(0);                                                      \
    }

#pragma unroll
    for (int step = 0; step < 15; ++step) {
        int cur = step & 1;
        int ns = step + 1;
        int tap = ns >> 2;
        int koff = ns * 64;
        int boff = dtab[tap] + (ns & 3) * 64;
#pragma unroll
        for (int it = 0; it < 4; ++it) {
            stage1k(srcA[it] + koff, &As[cur ^ 1][dstoff[it]]);
            stage1k(srcB[it] + boff, &Bs[cur ^ 1][dstoff[it]]);
        }
        asm volatile("s_waitcnt vmcnt(8)" ::: "memory");
        __builtin_amdgcn_s_barrier();
        asm volatile("" ::: "memory");
        if (cur == 0) { G2_COMPUTE(0); } else { G2_COMPUTE(1); }
        asm volatile("" ::: "memory");
        __builtin_amdgcn_s_barrier();
    }
    asm volatile("s_waitcnt vmcnt(0)" ::: "memory");
    __builtin_amdgcn_s_barrier();
    asm volatile("" ::: "memory");
    G2_COMPUTE(1)  // step 15: cur = 1
#undef G2_COMPUTE

    // coalesced bf16 write to parity-planar outP
#pragma unroll
    for (int mi = 0; mi < 4; ++mi) {
#pragma unroll
        for (int r = 0; r < 4; ++r) {
            int co = m0 + wm * 64 + mi * 16 + g * 4 + r;
            unsigned short* dst = outP + ((size_t)((p * 16 + b) * 256 + co) << 10) + pos0;
#pragma unroll
            for (int ni = 0; ni < 4; ++ni)
                dst[wn * 64 + ni * 16 + l15] = f2bf(acc[mi][ni][r]);
        }
    }
    // fused BN2 partial stats (from fp32 accs)
    float* sred  = (float*)&As[0][0];
    float* s2red = sred + 256;
#pragma unroll
    for (int mi = 0; mi < 4; ++mi) {
#pragma unroll
        for (int r = 0; r < 4; ++r) {
            float s = 0.f, s2 = 0.f;
#pragma unroll
            for (int ni = 0; ni < 4; ++ni) {
                float v = acc[mi][ni][r];
                s += v;
                s2 += v * v;
            }
#pragma unroll
            for (int m = 8; m >= 1; m >>= 1) {
                s  += __shfl_xor(s, m, 64);
                s2 += __shfl_xor(s2, m, 64);
            }
            if (l15 == 0) {
                int col = wm * 64 + mi * 16 + g * 4 + r;
                sred[col * 2 + wn]  = s;
                s2red[col * 2 + wn] = s2;
            }
        }
    }
    __syncthreads();
    if (t < 128) {
        float s  = sred[t * 2] + sred[t * 2 + 1];
        float s2 = s2red[t * 2] + s2red[t * 2 + 1];
        int row = p * 128 + nb;
        int ch = m0 + t;
        pstats2[ch * 512 + row] = s;
        pstats2[131072 + ch * 512 + row] = s2;
    }
}

// ---------------- parallel BN finisher ----------------
__global__ __launch_bounds__(256) void k_bnfin_par(const float* __restrict__ pstats, int nparts,
                                                   float n,
                                                   float* __restrict__ mean, float* __restrict__ rstd) {
    int ch = blockIdx.x;
    int t = threadIdx.x;
    float s = 0.f, s2 = 0.f;
    for (int j = t; j < nparts; j += 256) {
        s  += pstats[ch * nparts + j];
        s2 += pstats[256 * nparts + ch * nparts + j];
    }
    __shared__ float rs[256], rs2[256];
    rs[t] = s; rs2[t] = s2;
    __syncthreads();
    for (int d = 128; d > 0; d >>= 1) {
        if (t < d) { rs[t] += rs[t + d]; rs2[t] += rs2[t + d]; }
        __syncthreads();
    }
    if (t == 0) {
        float m = rs[0] / n;
        float var = rs2[0] / n - m * m;
        mean[ch] = m;
        rstd[ch] = rsqrtf(var + 1e-5f);
    }
}

// ---------------- BN+SiLU on bf16 y1 -> channel-last padded bf16 y1T, halo zeroed ----------------
__global__ __launch_bounds__(256) void k_bnsilu_padT(const unsigned short* __restrict__ y1b,
                                                     const float* __restrict__ mean,
                                                     const float* __restrict__ rstd,
                                                     const float* __restrict__ gamma,
                                                     const float* __restrict__ beta,
                                                     unsigned short* __restrict__ y1T) {
    int py = blockIdx.x, cg = blockIdx.y, b = blockIdx.z;
    int c0 = cg * 32;
    int t = threadIdx.x;
    uint2 zz; zz.x = 0u; zz.y = 0u;
    if (py == 0 || py == 33) {
        for (int u = t; u < 272; u += 256) {
            int col = u >> 3, c4 = (u & 7) * 4;
            *(uint2*)&y1T[((size_t)(b * 34 + py) * 34 + col) * 256 + c0 + c4] = zz;
        }
        return;
    }
    __shared__ unsigned short tl[32][36];
    int iy = py - 1;
    {
        int c_l = t >> 3, px4 = (t & 7) * 4;
        int ch = c0 + c_l;
        float m = mean[ch], rs = rstd[ch], ga = gamma[ch], be = beta[ch];
        uint2 v = *(const uint2*)&y1b[(size_t)((b * 256 + ch) << 10) + (iy << 5) + px4];
        float f0 = __uint_as_float(v.x << 16), f1 = __uint_as_float(v.x & 0xFFFF0000u);
        float f2 = __uint_as_float(v.y << 16), f3 = __uint_as_float(v.y & 0xFFFF0000u);
        tl[c_l][px4 + 0] = f2bf(silu(ga * (f0 - m) * rs + be));
        tl[c_l][px4 + 1] = f2bf(silu(ga * (f1 - m) * rs + be));
        tl[c_l][px4 + 2] = f2bf(silu(ga * (f2 - m) * rs + be));
        tl[c_l][px4 + 3] = f2bf(silu(ga * (f3 - m) * rs + be));
    }
    __syncthreads();
    {
        int px = t >> 3, c4 = (t & 7) * 4;
        unsigned int s0 = tl[c4 + 0][px];
        unsigned int s1 = tl[c4 + 1][px];
        unsigned int s2 = tl[c4 + 2][px];
        unsigned int s3 = tl[c4 + 3][px];
        uint2 pk;
        pk.x = s0 | (s1 << 16);
        pk.y = s2 | (s3 << 16);
        *(uint2*)&y1T[((size_t)(b * 34 + py) * 34 + (px + 1)) * 256 + c0 + c4] = pk;
    }
    if (t < 16) {
        int col = (t >> 3) ? 33 : 0;
        int c4 = (t & 7) * 4;
        *(uint2*)&y1T[((size_t)(b * 34 + py) * 34 + col) * 256 + c0 + c4] = zz;
    }
}

// ---------------- final: BN+SiLU + parity interleave (bf16 outP) -> out ----------------
__global__ __launch_bounds__(256) void k_bnsilu_out(const unsigned short* __restrict__ outP,
                                                    const float* __restrict__ mean,
                                                    const float* __restrict__ rstd,
                                                    const float* __restrict__ gamma,
                                                    const float* __restrict__ beta,
                                                    float* __restrict__ out) {
    unsigned int i = blockIdx.x * 256 + threadIdx.x;
    int ow4 = i & 15;
    int oh = (i >> 4) & 63;
    int co = (i >> 10) & 255;
    int b  = i >> 18;
    int p0 = (oh & 1) * 2;
    int pos = ((oh >> 1) << 5) + ow4 * 2;
    const unsigned short* pl0 = outP + ((size_t)((p0 * 16 + b) * 256 + co) << 10) + pos;
    const unsigned short* pl1 = pl0 + ((size_t)16 * 256 << 10);
    unsigned int ue = *(const unsigned int*)pl0;
    unsigned int uo = *(const unsigned int*)pl1;
    float ex = __uint_as_float(ue << 16), ey = __uint_as_float(ue & 0xFFFF0000u);
    float ox = __uint_as_float(uo << 16), oy = __uint_as_float(uo & 0xFFFF0000u);
    float m = mean[co], rs = rstd[co], ga = gamma[co], be = beta[co];
    float4 v;
    v.x = silu(ga * (ex - m) * rs + be);
    v.y = silu(ga * (ox - m) * rs + be);
    v.z = silu(ga * (ey - m) * rs + be);
    v.w = silu(ga * (oy - m) * rs + be);
    *(float4*)&out[((size_t)(b * 256 + co) << 12) + (oh << 6) + ow4 * 4] = v;
}

extern "C" void kernel_launch(void* const* d_in, const int* in_sizes, int n_in,
                              void* d_out, int out_size, void* d_ws, size_t ws_size,
                              hipStream_t stream) {
    const float* x      = (const float*)d_in[0];
    const float* w_off  = (const float*)d_in[1];
    const float* b_off  = (const float*)d_in[2];
    const float* w_def  = (const float*)d_in[3];
    const float* b_def  = (const float*)d_in[4];
    const float* gamma1 = (const float*)d_in[5];
    const float* beta1  = (const float*)d_in[6];
    const float* w_dc   = (const float*)d_in[7];
    const float* gamma2 = (const float*)d_in[8];
    const float* beta2  = (const float*)d_in[9];
    float* out = (float*)d_out;

    char* base = (char*)d_ws;
    unsigned short* S    = (unsigned short*)base;                 // 75,497,472 B (dead after gemm1)
    unsigned short* y1b  = (unsigned short*)(base + 75497472);    //  8,388,608 B (bf16)
    unsigned short* y1T  = (unsigned short*)(base + 92274688);    //  9,469,952 B (padded ch-last)
    unsigned short* A1   = (unsigned short*)(base + 101744640);   //  1,179,648 B
    unsigned short* A2   = (unsigned short*)(base + 102924288);   //  2,097,152 B
    float*          off  = (float*)(base + 105021440);            //  1,179,648 B
    float*          stats = (float*)(base + 106201088);           //  1,024 B
    float* mean1 = stats, *rstd1 = stats + 256, *mean2 = stats + 512, *rstd2 = stats + 768;
    float* pstats1 = off;
    float* pstats2 = off;
    unsigned short* xT    = (unsigned short*)base;                //  8,388,608 B (dead after off_gemm)
    unsigned short* A2off = (unsigned short*)(base + 8388608);    //    147,456 B
    unsigned short* outP = (unsigned short*)base;  // 33,554,432 B, aliases S after gemm1

    k_prep_all<<<10784, 256, 0, stream>>>(w_def, w_dc, w_off, x, A1, A2, A2off, xT);
    k_off_gemm<<<dim3(16, 16), 256, 0, stream>>>(A2off, xT, b_off, off);
    k_sample<<<dim3(32, 16), 576, 0, stream>>>(x, off, S);
    k_gemm1<<<dim3(256, 2), 256, 0, stream>>>(A1, S, b_def, y1b, pstats1);
    k_bnfin_par<<<256, 256, 0, stream>>>(pstats1, 256, 16384.f, mean1, rstd1);
    k_bnsilu_padT<<<dim3(34, 8, 16), 256, 0, stream>>>(y1b, mean1, rstd1, gamma1, beta1, y1T);
    k_gemm2<<<dim3(128, 2, 4), 256, 0, stream>>>(A2, y1T, outP, pstats2);
    k_bnfin_par<<<256, 256, 0, stream>>>(pstats2, 512, 65536.f, mean2, rstd2);
    k_bnsilu_out<<<16384, 256, 0, stream>>>(outP, mean2, rstd2, gamma2, beta2, out);
}